// Round 6
// baseline (470.437 us; speedup 1.0000x reference)
//
#include <hip/hip_runtime.h>
#include <hip/hip_bf16.h>
#include <stdint.h>

// Problem constants
#define S_DIM 4096
#define D_DIM 1024
#define KAUG  1088          // 1024 + 64 (LoRA-augmented K)
#define M_ROWS 8192         // B*S

typedef short bf16x8 __attribute__((ext_vector_type(8)));
typedef float f32x4  __attribute__((ext_vector_type(4)));

__device__ __forceinline__ f32x4 mfma16(bf16x8 a, bf16x8 b, f32x4 c) {
  return __builtin_amdgcn_mfma_f32_16x16x32_bf16(a, b, c, 0, 0, 0);
}
// precise RNE (used only in memory-bound prep)
__device__ __forceinline__ short f2bs(float f) {
  __hip_bfloat16 h = __float2bfloat16(f);
  return *reinterpret_cast<short*>(&h);
}
// fast 2-op bf16 cast: +0x8000 round, take high half (<=1 ulp vs RNE on ties)
__device__ __forceinline__ short f2bs_fast(float f) {
  unsigned u = __builtin_bit_cast(unsigned, f) + 0x8000u;
  return (short)(u >> 16);
}
// fast packed pair: 2 adds + 1 v_perm_b32 (a -> low16, b -> high16)
__device__ __forceinline__ unsigned pk2bf(float a, float b) {
  unsigned ua = __builtin_bit_cast(unsigned, a) + 0x8000u;
  unsigned ub = __builtin_bit_cast(unsigned, b) + 0x8000u;
  return __builtin_amdgcn_perm(ub, ua, 0x07060302);
}
__device__ __forceinline__ float bs2f(short s) {
  __hip_bfloat16 h;
  *reinterpret_cast<short*>(&h) = s;
  return __bfloat162float(h);
}
__device__ __forceinline__ float fexp2(float x) {
  return __builtin_amdgcn_exp2f(x);   // single v_exp_f32
}
__device__ __forceinline__ void gload16(const void* g, void* l) {
  __builtin_amdgcn_global_load_lds(
      (const __attribute__((address_space(1))) unsigned int*)g,
      (__attribute__((address_space(3))) unsigned int*)l, 16, 0, 0);
}

// ---------------- prep: casts + augmented operand construction ----------------
//  R1 xaug cols 0..1023 <- bf16(x)              8388608
//  R2 wqkv_aug (3072 x 1088)                    3342336
//  R3 wo_aug  (1024 x 1088)                     1114112
//  R4 l1cat   (64 x 1024)                       65536
//  R5 bias_cat (3072)                           3072
//  R6 cs2 interleaved float2 cos/sin table      131072
__global__ void prep_k(const float* __restrict__ x,
                       const float* __restrict__ wq, const float* __restrict__ wk,
                       const float* __restrict__ wv, const float* __restrict__ wo,
                       const float* __restrict__ wqb,
                       const float* __restrict__ lq1, const float* __restrict__ lq2,
                       const float* __restrict__ lk1, const float* __restrict__ lk2,
                       const float* __restrict__ lv1, const float* __restrict__ lv2,
                       const float* __restrict__ lo1, const float* __restrict__ lo2,
                       const float* __restrict__ cf, const float* __restrict__ sf,
                       short* __restrict__ xaug, short* __restrict__ wqkv,
                       short* __restrict__ woaug, short* __restrict__ l1cat,
                       float* __restrict__ biasc, float* __restrict__ cs2)
{
  unsigned i = blockIdx.x * 256u + threadIdx.x;
  if (i < 8388608u) {   // R1: x -> bf16 into xaug cols 0..1023
    unsigned m = i >> 10, k = i & 1023u;
    xaug[(size_t)m * KAUG + k] = f2bs(x[i]);
    return;
  }
  i -= 8388608u;
  if (i < 3342336u) {   // R2: wqkv_aug (3072 x 1088)
    unsigned n = i / 1088u, k = i - n * 1088u;
    float v;
    if (k < 1024u) {
      v = (n < 1024u) ? wq[n * 1024u + k]
        : (n < 2048u) ? wk[(n - 1024u) * 1024u + k]
                      : wv[(n - 2048u) * 1024u + k];
    } else {
      unsigned r = k - 1024u, blk = r >> 4, which = n >> 10;
      if (blk == which) {
        const float* l2 = which == 0 ? lq2 : which == 1 ? lk2 : lv2;
        v = l2[(n & 1023u) * 16u + (r & 15u)];
      } else v = 0.f;
    }
    wqkv[i] = f2bs(v);
    return;
  }
  i -= 3342336u;
  if (i < 1114112u) {   // R3: wo_aug (1024 x 1088)
    unsigned n = i / 1088u, k = i - n * 1088u;
    float v = (k < 1024u) ? wo[n * 1024u + k]
            : (k < 1040u) ? lo2[n * 16u + (k - 1024u)] : 0.f;
    woaug[i] = f2bs(v);
    return;
  }
  i -= 1114112u;
  if (i < 65536u) {     // R4: l1cat (64 x 1024)
    unsigned r = i >> 10, k = i & 1023u;
    const float* src = r < 16u ? lq1 : r < 32u ? lk1 : r < 48u ? lv1 : lo1;
    l1cat[i] = f2bs(src[(r & 15u) * 1024u + k]);
    return;
  }
  i -= 65536u;
  if (i < 3072u) {      // R5: bias_cat
    biasc[i] = (i < 1024u) ? wqb[i] : 0.f;
    return;
  }
  i -= 3072u;
  if (i < 131072u) {    // R6: interleaved cos/sin
    cs2[2u * i]     = cf[i];
    cs2[2u * i + 1] = sf[i];
  }
}

// ---------------- GEMM: C[m,n] = sum_k A[m,k]*B[n,k]  (B^T layout) -----------
// MODE 0: fp32 out + bias   MODE 1: bf16 out at [m*ldc+colofs+n]
// MODE 2: QKV scatter with FUSED RoPE on Q,K (Q also scaled by 0.125*log2e);
//         Q,K -> (B,H,S,HD); V -> transposed (B,H,HD,S) packed
template<int MODE>
__global__ __launch_bounds__(256) void gemm_bt(
    const short* __restrict__ A, int lda,
    const short* __restrict__ B, int ldb,
    int N, int K,
    const float* __restrict__ bias,
    void* __restrict__ Cout, int ldc, int colofs,
    short* __restrict__ qo, short* __restrict__ ko, short* __restrict__ vo,
    const float* __restrict__ cs2)
{
  __shared__ short As[128 * 32];
  __shared__ short Bs[128 * 32];
  const int tid = threadIdx.x;
  const int w = tid >> 6, lane = tid & 63;
  const int q4 = lane >> 4, c = lane & 15;
  const int mh = w >> 1, nh = w & 1;
  const int mt = blockIdx.y, nt = blockIdx.x;

  const int rl = lane >> 2;          // 0..15
  const int kc = (lane & 3) * 8;

  const short* Ag0 = A + (size_t)(mt * 128 + w * 32 + rl) * lda + kc;
  const short* Ag1 = Ag0 + (size_t)16 * lda;
  int rb0 = nt * 128 + w * 32 + rl;      if (rb0 > N - 1) rb0 = N - 1;
  int rb1 = nt * 128 + w * 32 + 16 + rl; if (rb1 > N - 1) rb1 = N - 1;
  const short* Bg0 = B + (size_t)rb0 * ldb + kc;
  const short* Bg1 = B + (size_t)rb1 * ldb + kc;
  short* as0 = &As[(w * 32) * 32];
  short* as1 = &As[(w * 32 + 16) * 32];
  short* bs0 = &Bs[(w * 32) * 32];
  short* bs1 = &Bs[(w * 32 + 16) * 32];

  f32x4 acc[4][4];
#pragma unroll
  for (int ms = 0; ms < 4; ++ms)
#pragma unroll
    for (int ns = 0; ns < 4; ++ns) acc[ms][ns] = (f32x4){0.f, 0.f, 0.f, 0.f};

  const int nkt = K >> 5;
  for (int kt = 0; kt < nkt; ++kt) {
    __syncthreads();
    gload16(Ag0, as0);
    gload16(Ag1, as1);
    gload16(Bg0, bs0);
    gload16(Bg1, bs1);
    Ag0 += 32; Ag1 += 32; Bg0 += 32; Bg1 += 32;
    __syncthreads();
    bf16x8 af[4], bfr[4];
#pragma unroll
    for (int ms = 0; ms < 4; ++ms)
      af[ms] = *(const bf16x8*)&As[(mh * 64 + ms * 16 + c) * 32 + q4 * 8];
#pragma unroll
    for (int ns = 0; ns < 4; ++ns)
      bfr[ns] = *(const bf16x8*)&Bs[(nh * 64 + ns * 16 + c) * 32 + q4 * 8];
#pragma unroll
    for (int ms = 0; ms < 4; ++ms)
#pragma unroll
      for (int ns = 0; ns < 4; ++ns)
        acc[ms][ns] = mfma16(af[ms], bfr[ns], acc[ms][ns]);
  }

#pragma unroll
  for (int ms = 0; ms < 4; ++ms) {
#pragma unroll
    for (int ns = 0; ns < 4; ++ns) {
      const int n = nt * 128 + nh * 64 + ns * 16 + c;
      if (MODE == 0) {
        float bsv = (n < N) ? bias[n] : 0.f;
        float* Co = (float*)Cout;
#pragma unroll
        for (int r = 0; r < 4; ++r) {
          int m = mt * 128 + mh * 64 + ms * 16 + q4 * 4 + r;
          if (n < N) Co[(size_t)m * ldc + n] = acc[ms][ns][r] + bsv;
        }
      } else if (MODE == 1) {
        short* Co = (short*)Cout;
#pragma unroll
        for (int r = 0; r < 4; ++r) {
          int m = mt * 128 + mh * 64 + ms * 16 + q4 * 4 + r;
          if (n < N) Co[(size_t)m * ldc + colofs + n] = f2bs_fast(acc[ms][ns][r]);
        }
      } else {
        float bsv = bias[n];
        int which = n >> 10;                  // wave-uniform per (nt,nh,ns)
        int m0 = mt * 128 + mh * 64 + ms * 16 + q4 * 4;
        int bb = m0 >> 12, spos = m0 & 4095;
        if (which < 2) {
          // fused RoPE: pair (even hd, odd hd) = adjacent lanes (c even/odd)
          int h = (n >> 6) & 15;
          int hd = n & 63;
          short* dst = which == 0 ? qo : ko;
          const float sgn = (c & 1) ? 1.f : -1.f;
          const int ihalf = hd >> 1;          // same for the lane pair
#pragma unroll
          for (int r = 0; r < 4; ++r) {
            float val = acc[ms][ns][r] + bsv;
            float part = __shfl_xor(val, 1);
            float2 cs = *(const float2*)&cs2[((size_t)(spos + r) * 32 + ihalf) * 2];
            // even lane: re = val*cc - part*ss ; odd lane: im = part*ss + val*cc
            float res = val * cs.x + part * (sgn * cs.y);
            if (which == 0) res *= 0.18033688011112042f;   // 0.125*log2e
            dst[(size_t)((bb * 16 + h) * 4096 + spos + r) * 64 + hd] = f2bs_fast(res);
          }
        } else {
          // V: write directly transposed (B,H,HD,S); 4 consecutive s -> 8B
          int h = (n >> 6) & 15;
          int hd = n & 63;
          uint2 vk;
          vk.x = pk2bf(acc[ms][ns][0] + bsv, acc[ms][ns][1] + bsv);
          vk.y = pk2bf(acc[ms][ns][2] + bsv, acc[ms][ns][3] + bsv);
          *(uint2*)&vo[(((size_t)bb * 16 + h) * 64 + hd) * 4096 + spos] = vk;
        }
      }
    }
  }
}

// ---------------- small-N skinny GEMM: BM=64, grid = M/64 blocks -------------
// C[m, colofs+n] = sum_k A[m,k]*B[n,k], N <= NT*16, bf16 out.
template<int NT>
__global__ __launch_bounds__(256) void tgemm_k(
    const short* __restrict__ A, int lda,
    const short* __restrict__ B, int ldb,
    int N, int K, short* __restrict__ C, int ldc, int colofs)
{
  __shared__ short As[64 * 32];
  __shared__ short Bs[64 * 32];
  const int tid = threadIdx.x;
  const int w = tid >> 6, lane = tid & 63;
  const int q4 = lane >> 4, c = lane & 15;
  const int rl = lane >> 2, kc = (lane & 3) * 8;
  const int arow = w * 16 + rl;
  const int brow = arow <= N - 1 ? arow : N - 1;

  const short* Ag = A + (size_t)(blockIdx.x * 64 + arow) * lda + kc;
  const short* Bg = B + (size_t)brow * ldb + kc;
  short* asd = &As[(w * 16) * 32];
  short* bsd = &Bs[(w * 16) * 32];

  f32x4 acc[NT];
#pragma unroll
  for (int i = 0; i < NT; ++i) acc[i] = (f32x4){0.f, 0.f, 0.f, 0.f};

  const int nkt = K >> 5;
  for (int kt = 0; kt < nkt; ++kt) {
    __syncthreads();
    gload16(Ag, asd);
    gload16(Bg, bsd);
    Ag += 32; Bg += 32;
    __syncthreads();
    bf16x8 af = *(const bf16x8*)&As[(w * 16 + c) * 32 + q4 * 8];
#pragma unroll
    for (int nsi = 0; nsi < NT; ++nsi) {
      bf16x8 bf = *(const bf16x8*)&Bs[(nsi * 16 + c) * 32 + q4 * 8];
      acc[nsi] = mfma16(af, bf, acc[nsi]);
    }
  }
#pragma unroll
  for (int nsi = 0; nsi < NT; ++nsi) {
#pragma unroll
    for (int r = 0; r < 4; ++r) {
      int m = blockIdx.x * 64 + w * 16 + q4 * 4 + r;
      int n = nsi * 16 + c;
      if (n < N) C[(size_t)m * ldc + colofs + n] = f2bs_fast(acc[nsi][r]);
    }
  }
}

// ---------------- Flash attention v5: QBLK=128, 40KB LDS, 4 blocks/CU --------
// Round-5 PMC: LDS ~67% busy, VALU 42%, MFMA 28%, occupancy 19.5% (8 waves/CU)
// -> pipes underoverlapped for lack of waves. Fix: shrink LDS/block 48->40KB
// so 4 blocks (16 waves) fit per CU:
//  * P/O slab SHARED between subtiles a and b (wave-private rows; same-wave
//    in-order DS pipe: pfa is in registers before Pb overwrites) -> PL 8KB
//  * Q staged through the K slabs at prologue (consumed to regs before K0)
// Grid de-paired: 1024 one-tile blocks, HEAVY-FIRST order (qt descending per
// XCD) -> LPT scheduling kills the tail; XCD bh-grouping retained (4MB L2).
// ZERO-REFERENCE softmax unchanged (P=exp2(s) bounded ~2^20, f32-safe).
// LDS (shorts): K dbuf @0/@4096, V dbuf @8192/@12288, PL @16384 (64x64)
//   = 40960 B total -> 4 blocks/CU at 160KB.
__global__ __launch_bounds__(256, 4) void flash_k(
    const short* __restrict__ Qb, const short* __restrict__ Kb,
    const short* __restrict__ Vt, short* __restrict__ Oaug)
{
  __shared__ short lds[20480];
  short* const PL = &lds[16384];

  // id -> (XCD g, bh, qt): 128 ids per XCD, 4 bh each, qt DESCENDING (heavy
  // blocks dispatch first -> no straggler tail).
  const int id = (int)blockIdx.y * 32 + (int)blockIdx.x;   // 0..1023
  const int g = id & 7, j = id >> 3;                       // j in 0..127
  const int bh = g * 4 + (j >> 5);
  const int qt = 31 - (j & 31);                            // 128-row q-tile

  const int tid = threadIdx.x;
  const int w = tid >> 6, lane = tid & 63;
  const int q4 = lane >> 4, c = lane & 15;

  const short* Kg = Kb + (size_t)bh * 4096 * 64;
  const short* Vg = Vt + (size_t)bh * 64 * 4096;
  const short* Qg = Qb + ((size_t)bh * 4096 + qt * 128) * 64;

  // staging source offsets (shorts), XOR-swizzled chunk layout
  const int l8 = lane >> 3, l7 = lane & 7;
  const int sw = (l7 ^ l8) * 8;
  const int G0 = w * 2, G1 = w * 2 + 1;
  const int koff0 = (G0 * 8 + l8) * 64 + sw;       // K: row-major rows
  const int koff1 = (G1 * 8 + l8) * 64 + sw;
  const int voff0 = (G0 * 8 + l8) * 4096 + sw;     // V^T: hd-major rows
  const int voff1 = (G1 * 8 + l8) * 4096 + sw;
  // Q staging: 16 groups (128 rows) through the two K slabs
  const int qg = w * 4;
  const int qoff0 = ((qg + 0) * 8 + l8) * 64 + sw;
  const int qoff1 = ((qg + 1) * 8 + l8) * 64 + sw;
  const int qoff2 = ((qg + 2) * 8 + l8) * 64 + sw;
  const int qoff3 = ((qg + 3) * 8 + l8) * 64 + sw;

  // fragment read offsets (shorts)
  const int c7 = c & 7;
  const int chA0 = ((q4) ^ c7) * 8;                // k-chunk t=0
  const int chA1 = ((4 + q4) ^ c7) * 8;            // k-chunk t=1
  const int rowc = c * 64;                         // K/V row = (blk*16 + c)
  const int rowq = (w * 16 + c) * 64;              // wave's q/P/O row
  const int pw_base = (w * 16 + c) * 64 + (q4 & 1) * 4;
  const int pw_g = q4 >> 1;

  const int b = bh >> 4, h = bh & 15;

  // ---- prologue: Q through K slabs -> regs; then K0/V0 staging ----
  gload16(Qg + qoff0, &lds[(qg + 0) * 512]);
  gload16(Qg + qoff1, &lds[(qg + 1) * 512]);
  gload16(Qg + qoff2, &lds[(qg + 2) * 512]);
  gload16(Qg + qoff3, &lds[(qg + 3) * 512]);
  __syncthreads();
  bf16x8 qa0 = *(const bf16x8*)(&lds[0] + rowq + chA0);
  bf16x8 qa1 = *(const bf16x8*)(&lds[0] + rowq + chA1);
  bf16x8 qb0 = *(const bf16x8*)(&lds[4096] + rowq + chA0);
  bf16x8 qb1 = *(const bf16x8*)(&lds[4096] + rowq + chA1);
  __syncthreads();                     // all waves consumed Q
  gload16(Kg + koff0, &lds[G0 * 512]);
  gload16(Kg + koff1, &lds[G1 * 512]);
  gload16(Vg + voff0, &lds[8192 + G0 * 512]);
  gload16(Vg + voff1, &lds[8192 + G1 * 512]);
  __syncthreads();                     // tile 0 staged

  f32x4 oa[4], ob[4];
#pragma unroll
  for (int i = 0; i < 4; ++i) {
    oa[i] = (f32x4){0.f, 0.f, 0.f, 0.f};
    ob[i] = (f32x4){0.f, 0.f, 0.f, 0.f};
  }
  float la = 0.f, lb = 0.f;

  const int last = 2 * qt + 1;
  for (int kt = 0; kt <= last; ++kt) {
    const int cur = (kt & 1) * 4096;
    const short* Kc = &lds[cur];
    const short* Vc = &lds[8192 + cur];
    if (kt < last) {                   // prefetch next tile (overlaps compute)
      const int nxt = ((kt + 1) & 1) * 4096;
      const short* ks = Kg + (size_t)(kt + 1) * 4096;
      const short* vs = Vg + (size_t)(kt + 1) * 64;
      gload16(ks + koff0, &lds[nxt + G0 * 512]);
      gload16(ks + koff1, &lds[nxt + G1 * 512]);
      gload16(vs + voff0, &lds[8192 + nxt + G0 * 512]);
      gload16(vs + voff1, &lds[8192 + nxt + G1 * 512]);
    }
    const bool doA = (kt <= 2 * qt);   // a skips the final kv-tile

    // S^T = K·Q^T for both subtiles from ONE K-fragment load
    f32x4 sa[4], sb[4];
#pragma unroll
    for (int ns = 0; ns < 4; ++ns) {
      bf16x8 kf0 = *(const bf16x8*)(Kc + ns * 1024 + rowc + chA0);
      bf16x8 kf1 = *(const bf16x8*)(Kc + ns * 1024 + rowc + chA1);
      sa[ns] = mfma16(kf0, qa0, (f32x4){0.f, 0.f, 0.f, 0.f});
      sa[ns] = mfma16(kf1, qa1, sa[ns]);
      sb[ns] = mfma16(kf0, qb0, (f32x4){0.f, 0.f, 0.f, 0.f});
      sb[ns] = mfma16(kf1, qb1, sb[ns]);
    }
    if (kt == 2 * qt) {                // diagonal for subtile a
#pragma unroll
      for (int ns = 0; ns < 4; ++ns)
#pragma unroll
        for (int r = 0; r < 4; ++r)
          if (ns * 16 + q4 * 4 + r > w * 16 + c) sa[ns][r] = -1e30f;
    }
    if (kt == last) {                  // diagonal for subtile b
#pragma unroll
      for (int ns = 0; ns < 4; ++ns)
#pragma unroll
        for (int r = 0; r < 4; ++r)
          if (ns * 16 + q4 * 4 + r > w * 16 + c) sb[ns][r] = -1e30f;
    }

    bf16x8 pfa0, pfa1;
    if (doA) {                         // softmax a; P_a through shared slab
      float ps[4][4];
#pragma unroll
      for (int ns = 0; ns < 4; ++ns)
#pragma unroll
        for (int r = 0; r < 4; ++r) ps[ns][r] = fexp2(sa[ns][r]);
      float s0 = (ps[0][0] + ps[0][1]) + (ps[0][2] + ps[0][3]);
      float s1 = (ps[1][0] + ps[1][1]) + (ps[1][2] + ps[1][3]);
      float s2 = (ps[2][0] + ps[2][1]) + (ps[2][2] + ps[2][3]);
      float s3 = (ps[3][0] + ps[3][1]) + (ps[3][2] + ps[3][3]);
      float sum = (s0 + s1) + (s2 + s3);
      sum += __shfl_xor(sum, 16);
      sum += __shfl_xor(sum, 32);
      la += sum;
#pragma unroll
      for (int ns = 0; ns < 4; ++ns) {
        uint2 pk;
        pk.x = pk2bf(ps[ns][0], ps[ns][1]);
        pk.y = pk2bf(ps[ns][2], ps[ns][3]);
        *(uint2*)(PL + pw_base + (((ns * 2 + pw_g) ^ c7) * 8)) = pk;
      }
      pfa0 = *(const bf16x8*)(PL + rowq + chA0);  // into regs before Pb write
      pfa1 = *(const bf16x8*)(PL + rowq + chA1);
    }
    {                                  // softmax b; P_b reuses the SAME slab
      float ps[4][4];
#pragma unroll
      for (int ns = 0; ns < 4; ++ns)
#pragma unroll
        for (int r = 0; r < 4; ++r) ps[ns][r] = fexp2(sb[ns][r]);
      float s0 = (ps[0][0] + ps[0][1]) + (ps[0][2] + ps[0][3]);
      float s1 = (ps[1][0] + ps[1][1]) + (ps[1][2] + ps[1][3]);
      float s2 = (ps[2][0] + ps[2][1]) + (ps[2][2] + ps[2][3]);
      float s3 = (ps[3][0] + ps[3][1]) + (ps[3][2] + ps[3][3]);
      float sum = (s0 + s1) + (s2 + s3);
      sum += __shfl_xor(sum, 16);
      sum += __shfl_xor(sum, 32);
      lb += sum;
#pragma unroll
      for (int ns = 0; ns < 4; ++ns) {
        uint2 pk;
        pk.x = pk2bf(ps[ns][0], ps[ns][1]);
        pk.y = pk2bf(ps[ns][2], ps[ns][3]);
        *(uint2*)(PL + pw_base + (((ns * 2 + pw_g) ^ c7) * 8)) = pk;
      }
    }
    bf16x8 pfb0 = *(const bf16x8*)(PL + rowq + chA0);
    bf16x8 pfb1 = *(const bf16x8*)(PL + rowq + chA1);

    // O^T += V^T·P^T, both subtiles from ONE V-fragment load
#pragma unroll
    for (int nc = 0; nc < 4; ++nc) {
      bf16x8 vf0 = *(const bf16x8*)(Vc + nc * 1024 + rowc + chA0);
      bf16x8 vf1 = *(const bf16x8*)(Vc + nc * 1024 + rowc + chA1);
      if (doA) {
        oa[nc] = mfma16(vf0, pfa0, oa[nc]);
        oa[nc] = mfma16(vf1, pfa1, oa[nc]);
      }
      ob[nc] = mfma16(vf0, pfb0, ob[nc]);
      ob[nc] = mfma16(vf1, pfb1, ob[nc]);
    }
    __syncthreads();                   // drains prefetch; frees cur buffers
  }

  // ---- epilogue: two passes through the shared 8KB slab ----
  float lia = 1.f / la, lib = 1.f / lb;
#pragma unroll
  for (int nc = 0; nc < 4; ++nc) {
    uint2 ok;
    ok.x = pk2bf(oa[nc][0] * lia, oa[nc][1] * lia);
    ok.y = pk2bf(oa[nc][2] * lia, oa[nc][3] * lia);
    *(uint2*)(PL + pw_base + (((nc * 2 + pw_g) ^ c7) * 8)) = ok;
  }
  __syncthreads();
#pragma unroll
  for (int i2 = 0; i2 < 2; ++i2) {
    int ch = tid + i2 * 256;           // 512 chunks = 64 rows x 8
    int r = ch >> 3, g2 = ch & 7;
    size_t row = (size_t)b * 4096 + qt * 128 + r;
    *(int4*)&Oaug[row * KAUG + h * 64 + g2 * 8] =
        *(const int4*)(PL + r * 64 + ((g2 ^ (r & 7)) * 8));
  }
  __syncthreads();
#pragma unroll
  for (int nc = 0; nc < 4; ++nc) {
    uint2 ok;
    ok.x = pk2bf(ob[nc][0] * lib, ob[nc][1] * lib);
    ok.y = pk2bf(ob[nc][2] * lib, ob[nc][3] * lib);
    *(uint2*)(PL + pw_base + (((nc * 2 + pw_g) ^ c7) * 8)) = ok;
  }
  __syncthreads();
#pragma unroll
  for (int i2 = 0; i2 < 2; ++i2) {
    int ch = tid + i2 * 256;
    int r = ch >> 3, g2 = ch & 7;
    size_t row = (size_t)b * 4096 + qt * 128 + 64 + r;
    *(int4*)&Oaug[row * KAUG + h * 64 + g2 * 8] =
        *(const int4*)(PL + r * 64 + ((g2 ^ (r & 7)) * 8));
  }
}

// ---------------- host launch ------------------------------------------------
extern "C" void kernel_launch(void* const* d_in, const int* in_sizes, int n_in,
                              void* d_out, int out_size, void* d_ws, size_t ws_size,
                              hipStream_t stream) {
  const float* x   = (const float*)d_in[0];
  const float* fc  = (const float*)d_in[1];
  const float* fs  = (const float*)d_in[2];
  // d_in[3] = mask (causal, reimplemented analytically)
  const float* wq  = (const float*)d_in[4];
  const float* wqb = (const float*)d_in[5];
  const float* wk  = (const float*)d_in[6];
  const float* wv  = (const float*)d_in[7];
  const float* wo  = (const float*)d_in[8];
  const float* wob = (const float*)d_in[9];
  const float* lq1 = (const float*)d_in[10];
  const float* lq2 = (const float*)d_in[11];
  const float* lk1 = (const float*)d_in[12];
  const float* lk2 = (const float*)d_in[13];
  const float* lv1 = (const float*)d_in[14];
  const float* lv2 = (const float*)d_in[15];
  const float* lo1 = (const float*)d_in[16];
  const float* lo2 = (const float*)d_in[17];

  char* ws = (char*)d_ws;
  const size_t OFF_XAUG  = 0;
  const size_t OFF_XOAUG = 17825792;
  const size_t OFF_WQKV  = 35651584;
  const size_t OFF_WOAUG = 42336256;
  const size_t OFF_L1CAT = 44564480;
  const size_t OFF_BIASC = 44695552;
  const size_t OFF_QB    = 44707840;
  const size_t OFF_KB    = 61485056;
  const size_t OFF_VT    = 78262272;
  const size_t OFF_CS    = 95039488;   // 131072 float2 = 1 MiB

  short* xaug  = (short*)(ws + OFF_XAUG);
  short* xoaug = (short*)(ws + OFF_XOAUG);
  short* wqkv  = (short*)(ws + OFF_WQKV);
  short* woaug = (short*)(ws + OFF_WOAUG);
  short* l1cat = (short*)(ws + OFF_L1CAT);
  float* biasc = (float*)(ws + OFF_BIASC);
  short* qb    = (short*)(ws + OFF_QB);
  short* kb    = (short*)(ws + OFF_KB);
  short* vt    = (short*)(ws + OFF_VT);
  float* cs2   = (float*)(ws + OFF_CS);

  // 13044736 elements total = exactly 50956 blocks
  prep_k<<<50956, 256, 0, stream>>>(x, wq, wk, wv, wo, wqb,
                                    lq1, lq2, lk1, lk2, lv1, lv2, lo1, lo2,
                                    fc, fs,
                                    xaug, wqkv, woaug, l1cat, biasc, cs2);
  // T_qkv = x @ [lq1;lk1;lv1]^T -> xaug cols 1024..1071 (128 blocks)
  tgemm_k<3><<<128, 256, 0, stream>>>(xaug, KAUG, l1cat, 1024, 48, 1024,
                                      xaug, KAUG, 1024);
  // fused QKV projection + bias + RoPE -> qb,kb (B,H,S,HD), vt (B,H,HD,S)
  gemm_bt<2><<<dim3(24, 64), 256, 0, stream>>>(xaug, KAUG, wqkv, KAUG, 3072, KAUG,
                                               biasc, nullptr, 0, 0, qb, kb, vt,
                                               cs2);
  // flash attention -> xoaug cols 0..1023 (1024 blocks, QBLK=128, heavy-first)
  flash_k<<<dim3(32, 32), 256, 0, stream>>>(qb, kb, vt, xoaug);
  // T_o = attn_out @ lo1^T -> xoaug cols 1024..1039 (128 blocks)
  tgemm_k<1><<<128, 256, 0, stream>>>(xoaug, KAUG, l1cat + 48 * 1024, 1024,
                                      16, 1024, xoaug, KAUG, 1024);
  // final projection -> d_out (fp32)
  gemm_bt<0><<<dim3(8, 64), 256, 0, stream>>>(xoaug, KAUG, woaug, KAUG, 1024, KAUG,
                                              wob, d_out, 1024, 0,
                                              nullptr, nullptr, nullptr, nullptr);
}

// Round 7
// 396.494 us; speedup vs baseline: 1.1865x; 1.1865x over previous
//
#include <hip/hip_runtime.h>
#include <hip/hip_bf16.h>
#include <stdint.h>

// Problem constants
#define S_DIM 4096
#define D_DIM 1024
#define KAUG  1088          // 1024 + 64 (LoRA-augmented K)
#define M_ROWS 8192         // B*S

typedef short bf16x8 __attribute__((ext_vector_type(8)));
typedef float f32x4  __attribute__((ext_vector_type(4)));

__device__ __forceinline__ f32x4 mfma16(bf16x8 a, bf16x8 b, f32x4 c) {
  return __builtin_amdgcn_mfma_f32_16x16x32_bf16(a, b, c, 0, 0, 0);
}
// precise RNE (used only in memory-bound prep)
__device__ __forceinline__ short f2bs(float f) {
  __hip_bfloat16 h = __float2bfloat16(f);
  return *reinterpret_cast<short*>(&h);
}
// fast 2-op bf16 cast: +0x8000 round, take high half (<=1 ulp vs RNE on ties)
__device__ __forceinline__ short f2bs_fast(float f) {
  unsigned u = __builtin_bit_cast(unsigned, f) + 0x8000u;
  return (short)(u >> 16);
}
// fast packed pair: 2 adds + 1 v_perm_b32 (a -> low16, b -> high16)
__device__ __forceinline__ unsigned pk2bf(float a, float b) {
  unsigned ua = __builtin_bit_cast(unsigned, a) + 0x8000u;
  unsigned ub = __builtin_bit_cast(unsigned, b) + 0x8000u;
  return __builtin_amdgcn_perm(ub, ua, 0x07060302);
}
__device__ __forceinline__ float bs2f(short s) {
  __hip_bfloat16 h;
  *reinterpret_cast<short*>(&h) = s;
  return __bfloat162float(h);
}
__device__ __forceinline__ float fexp2(float x) {
  return __builtin_amdgcn_exp2f(x);   // single v_exp_f32
}
__device__ __forceinline__ void gload16(const void* g, void* l) {
  __builtin_amdgcn_global_load_lds(
      (const __attribute__((address_space(1))) unsigned int*)g,
      (__attribute__((address_space(3))) unsigned int*)l, 16, 0, 0);
}

// ---------------- prep: casts + augmented operand construction ----------------
//  R1 xaug cols 0..1023 <- bf16(x)              8388608
//  R2 wqkv_aug (3072 x 1088)                    3342336
//  R3 wo_aug  (1024 x 1088)                     1114112
//  R4 l1cat   (64 x 1024)                       65536
//  R5 bias_cat (3072)                           3072
//  R6 cs2 interleaved float2 cos/sin table      131072
__global__ void prep_k(const float* __restrict__ x,
                       const float* __restrict__ wq, const float* __restrict__ wk,
                       const float* __restrict__ wv, const float* __restrict__ wo,
                       const float* __restrict__ wqb,
                       const float* __restrict__ lq1, const float* __restrict__ lq2,
                       const float* __restrict__ lk1, const float* __restrict__ lk2,
                       const float* __restrict__ lv1, const float* __restrict__ lv2,
                       const float* __restrict__ lo1, const float* __restrict__ lo2,
                       const float* __restrict__ cf, const float* __restrict__ sf,
                       short* __restrict__ xaug, short* __restrict__ wqkv,
                       short* __restrict__ woaug, short* __restrict__ l1cat,
                       float* __restrict__ biasc, float* __restrict__ cs2)
{
  unsigned i = blockIdx.x * 256u + threadIdx.x;
  if (i < 8388608u) {   // R1: x -> bf16 into xaug cols 0..1023
    unsigned m = i >> 10, k = i & 1023u;
    xaug[(size_t)m * KAUG + k] = f2bs(x[i]);
    return;
  }
  i -= 8388608u;
  if (i < 3342336u) {   // R2: wqkv_aug (3072 x 1088)
    unsigned n = i / 1088u, k = i - n * 1088u;
    float v;
    if (k < 1024u) {
      v = (n < 1024u) ? wq[n * 1024u + k]
        : (n < 2048u) ? wk[(n - 1024u) * 1024u + k]
                      : wv[(n - 2048u) * 1024u + k];
    } else {
      unsigned r = k - 1024u, blk = r >> 4, which = n >> 10;
      if (blk == which) {
        const float* l2 = which == 0 ? lq2 : which == 1 ? lk2 : lv2;
        v = l2[(n & 1023u) * 16u + (r & 15u)];
      } else v = 0.f;
    }
    wqkv[i] = f2bs(v);
    return;
  }
  i -= 3342336u;
  if (i < 1114112u) {   // R3: wo_aug (1024 x 1088)
    unsigned n = i / 1088u, k = i - n * 1088u;
    float v = (k < 1024u) ? wo[n * 1024u + k]
            : (k < 1040u) ? lo2[n * 16u + (k - 1024u)] : 0.f;
    woaug[i] = f2bs(v);
    return;
  }
  i -= 1114112u;
  if (i < 65536u) {     // R4: l1cat (64 x 1024)
    unsigned r = i >> 10, k = i & 1023u;
    const float* src = r < 16u ? lq1 : r < 32u ? lk1 : r < 48u ? lv1 : lo1;
    l1cat[i] = f2bs(src[(r & 15u) * 1024u + k]);
    return;
  }
  i -= 65536u;
  if (i < 3072u) {      // R5: bias_cat
    biasc[i] = (i < 1024u) ? wqb[i] : 0.f;
    return;
  }
  i -= 3072u;
  if (i < 131072u) {    // R6: interleaved cos/sin
    cs2[2u * i]     = cf[i];
    cs2[2u * i + 1] = sf[i];
  }
}

// ---------------- GEMM: C[m,n] = sum_k A[m,k]*B[n,k]  (B^T layout) -----------
// 2-PHASE DOUBLE-BUFFER (T3 minimum recipe): stage tile kt+1 into buf^1
// BEFORE computing tile kt; ONE vmcnt-draining barrier per K-step (was: drain
// BEFORE compute, zero overlap). Race-safe: buf nxt was last read in iter
// kt-1 whose end barrier all waves passed; end-of-iter __syncthreads drains
// vmcnt so tile kt+1 is resident before use.
// MODE 0: fp32 out + bias   MODE 1: bf16 out at [m*ldc+colofs+n]
// MODE 2: QKV scatter with FUSED RoPE on Q,K (Q also scaled by 0.125*log2e);
//         Q,K -> (B,H,S,HD); V -> transposed (B,H,HD,S) packed
template<int MODE>
__global__ __launch_bounds__(256) void gemm_bt(
    const short* __restrict__ A, int lda,
    const short* __restrict__ B, int ldb,
    int N, int K,
    const float* __restrict__ bias,
    void* __restrict__ Cout, int ldc, int colofs,
    short* __restrict__ qo, short* __restrict__ ko, short* __restrict__ vo,
    const float* __restrict__ cs2)
{
  __shared__ short As[2][128 * 32];
  __shared__ short Bs[2][128 * 32];
  const int tid = threadIdx.x;
  const int w = tid >> 6, lane = tid & 63;
  const int q4 = lane >> 4, c = lane & 15;
  const int mh = w >> 1, nh = w & 1;
  const int mt = blockIdx.y, nt = blockIdx.x;

  const int rl = lane >> 2;          // 0..15
  const int kc = (lane & 3) * 8;

  const short* Ag0 = A + (size_t)(mt * 128 + w * 32 + rl) * lda + kc;
  const short* Ag1 = Ag0 + (size_t)16 * lda;
  int rb0 = nt * 128 + w * 32 + rl;      if (rb0 > N - 1) rb0 = N - 1;
  int rb1 = nt * 128 + w * 32 + 16 + rl; if (rb1 > N - 1) rb1 = N - 1;
  const short* Bg0 = B + (size_t)rb0 * ldb + kc;
  const short* Bg1 = B + (size_t)rb1 * ldb + kc;
  const int sD0 = (w * 32) * 32;         // staging dest offsets (shorts)
  const int sD1 = (w * 32 + 16) * 32;

  f32x4 acc[4][4];
#pragma unroll
  for (int ms = 0; ms < 4; ++ms)
#pragma unroll
    for (int ns = 0; ns < 4; ++ns) acc[ms][ns] = (f32x4){0.f, 0.f, 0.f, 0.f};

  // prologue: tile 0 -> buf 0
  gload16(Ag0, &As[0][sD0]);
  gload16(Ag1, &As[0][sD1]);
  gload16(Bg0, &Bs[0][sD0]);
  gload16(Bg1, &Bs[0][sD1]);
  Ag0 += 32; Ag1 += 32; Bg0 += 32; Bg1 += 32;
  __syncthreads();                       // drains prologue staging

  const int nkt = K >> 5;
  for (int kt = 0; kt < nkt; ++kt) {
    const int cur = kt & 1, nxt = cur ^ 1;
    if (kt + 1 < nkt) {                  // prefetch next tile (overlaps compute)
      gload16(Ag0, &As[nxt][sD0]);
      gload16(Ag1, &As[nxt][sD1]);
      gload16(Bg0, &Bs[nxt][sD0]);
      gload16(Bg1, &Bs[nxt][sD1]);
      Ag0 += 32; Ag1 += 32; Bg0 += 32; Bg1 += 32;
    }
    bf16x8 af[4], bfr[4];
#pragma unroll
    for (int ms = 0; ms < 4; ++ms)
      af[ms] = *(const bf16x8*)&As[cur][(mh * 64 + ms * 16 + c) * 32 + q4 * 8];
#pragma unroll
    for (int ns = 0; ns < 4; ++ns)
      bfr[ns] = *(const bf16x8*)&Bs[cur][(nh * 64 + ns * 16 + c) * 32 + q4 * 8];
#pragma unroll
    for (int ms = 0; ms < 4; ++ms)
#pragma unroll
      for (int ns = 0; ns < 4; ++ns)
        acc[ms][ns] = mfma16(af[ms], bfr[ns], acc[ms][ns]);
    __syncthreads();                     // next tile staged; cur free to reuse
  }

#pragma unroll
  for (int ms = 0; ms < 4; ++ms) {
#pragma unroll
    for (int ns = 0; ns < 4; ++ns) {
      const int n = nt * 128 + nh * 64 + ns * 16 + c;
      if (MODE == 0) {
        float bsv = (n < N) ? bias[n] : 0.f;
        float* Co = (float*)Cout;
#pragma unroll
        for (int r = 0; r < 4; ++r) {
          int m = mt * 128 + mh * 64 + ms * 16 + q4 * 4 + r;
          if (n < N) Co[(size_t)m * ldc + n] = acc[ms][ns][r] + bsv;
        }
      } else if (MODE == 1) {
        short* Co = (short*)Cout;
#pragma unroll
        for (int r = 0; r < 4; ++r) {
          int m = mt * 128 + mh * 64 + ms * 16 + q4 * 4 + r;
          if (n < N) Co[(size_t)m * ldc + colofs + n] = f2bs_fast(acc[ms][ns][r]);
        }
      } else {
        float bsv = bias[n];
        int which = n >> 10;                  // wave-uniform per (nt,nh,ns)
        int m0 = mt * 128 + mh * 64 + ms * 16 + q4 * 4;
        int bb = m0 >> 12, spos = m0 & 4095;
        if (which < 2) {
          // fused RoPE: pair (even hd, odd hd) = adjacent lanes (c even/odd)
          int h = (n >> 6) & 15;
          int hd = n & 63;
          short* dst = which == 0 ? qo : ko;
          const float sgn = (c & 1) ? 1.f : -1.f;
          const int ihalf = hd >> 1;          // same for the lane pair
#pragma unroll
          for (int r = 0; r < 4; ++r) {
            float val = acc[ms][ns][r] + bsv;
            float part = __shfl_xor(val, 1);
            float2 cs = *(const float2*)&cs2[((size_t)(spos + r) * 32 + ihalf) * 2];
            // even lane: re = val*cc - part*ss ; odd lane: im = part*ss + val*cc
            float res = val * cs.x + part * (sgn * cs.y);
            if (which == 0) res *= 0.18033688011112042f;   // 0.125*log2e
            dst[(size_t)((bb * 16 + h) * 4096 + spos + r) * 64 + hd] = f2bs_fast(res);
          }
        } else {
          // V: write directly transposed (B,H,HD,S); 4 consecutive s -> 8B
          int h = (n >> 6) & 15;
          int hd = n & 63;
          uint2 vk;
          vk.x = pk2bf(acc[ms][ns][0] + bsv, acc[ms][ns][1] + bsv);
          vk.y = pk2bf(acc[ms][ns][2] + bsv, acc[ms][ns][3] + bsv);
          *(uint2*)&vo[(((size_t)bb * 16 + h) * 64 + hd) * 4096 + spos] = vk;
        }
      }
    }
  }
}

// ---------------- small-N skinny GEMM: BM=64, grid = M/64 blocks -------------
// Same 2-phase double-buffer as gemm_bt. N <= NT*16, bf16 out.
template<int NT>
__global__ __launch_bounds__(256) void tgemm_k(
    const short* __restrict__ A, int lda,
    const short* __restrict__ B, int ldb,
    int N, int K, short* __restrict__ C, int ldc, int colofs)
{
  __shared__ short As[2][64 * 32];
  __shared__ short Bs[2][64 * 32];
  const int tid = threadIdx.x;
  const int w = tid >> 6, lane = tid & 63;
  const int q4 = lane >> 4, c = lane & 15;
  const int rl = lane >> 2, kc = (lane & 3) * 8;
  const int arow = w * 16 + rl;
  const int brow = arow <= N - 1 ? arow : N - 1;

  const short* Ag = A + (size_t)(blockIdx.x * 64 + arow) * lda + kc;
  const short* Bg = B + (size_t)brow * ldb + kc;
  const int sD = (w * 16) * 32;

  f32x4 acc[NT];
#pragma unroll
  for (int i = 0; i < NT; ++i) acc[i] = (f32x4){0.f, 0.f, 0.f, 0.f};

  // prologue: tile 0 -> buf 0
  gload16(Ag, &As[0][sD]);
  gload16(Bg, &Bs[0][sD]);
  Ag += 32; Bg += 32;
  __syncthreads();

  const int nkt = K >> 5;
  for (int kt = 0; kt < nkt; ++kt) {
    const int cur = kt & 1, nxt = cur ^ 1;
    if (kt + 1 < nkt) {
      gload16(Ag, &As[nxt][sD]);
      gload16(Bg, &Bs[nxt][sD]);
      Ag += 32; Bg += 32;
    }
    bf16x8 af = *(const bf16x8*)&As[cur][(w * 16 + c) * 32 + q4 * 8];
#pragma unroll
    for (int nsi = 0; nsi < NT; ++nsi) {
      bf16x8 bf = *(const bf16x8*)&Bs[cur][(nsi * 16 + c) * 32 + q4 * 8];
      acc[nsi] = mfma16(af, bf, acc[nsi]);
    }
    __syncthreads();
  }
#pragma unroll
  for (int nsi = 0; nsi < NT; ++nsi) {
#pragma unroll
    for (int r = 0; r < 4; ++r) {
      int m = blockIdx.x * 64 + w * 16 + q4 * 4 + r;
      int n = nsi * 16 + c;
      if (n < N) C[(size_t)m * ldc + colofs + n] = f2bs_fast(acc[nsi][r]);
    }
  }
}

// ---------------- Flash attention v4 (round-5 state, measured 107 us) --------
// QBLK=128, paired q-tiles (31-bx, bx): uniform 68 KV-iters per block; 512
// blocks, 2/CU resident, 48KB LDS. At the ds_read_b128 issue ceiling (m134
// ~85 B/cyc): 80 b128/block-iter x 12cyc ~= the 945-cyc measured period --
// this design family's structural floor. Reverted from the round-6 de-paired
// variant (co-resident imbalance regression).
// ZERO-REFERENCE softmax: P = exp2(s) bounded ~2^20, f32-safe, o/l exact.
// XCD swizzle: id%8 = XCD g hosts bh in {4g..4g+3} (per-XCD K/V set = 4MB L2).
// LDS (shorts): K dbuf @0/@4096, V dbuf @8192/@12288, PL @16384 (128x64:
// Q staging, then P/O; subtile b at +4096) = 49152 B total.
__global__ __launch_bounds__(256, 2) void flash_k(
    const short* __restrict__ Qb, const short* __restrict__ Kb,
    const short* __restrict__ Vt, short* __restrict__ Oaug)
{
  __shared__ short lds[24576];
  short* const PL = &lds[16384];

  const int id = (int)blockIdx.y * 16 + (int)blockIdx.x;   // 0..511
  const int g = id & 7, j = id >> 3;                       // j in 0..63
  const int bh = g * 4 + (j >> 4);
  const int bx = j & 15;

  const int tid = threadIdx.x;
  const int w = tid >> 6, lane = tid & 63;
  const int q4 = lane >> 4, c = lane & 15;

  const short* Kg = Kb + (size_t)bh * 4096 * 64;
  const short* Vg = Vt + (size_t)bh * 64 * 4096;

  // staging source offsets (shorts), XOR-swizzled chunk layout
  const int l8 = lane >> 3, l7 = lane & 7;
  const int sw = (l7 ^ l8) * 8;
  const int G0 = w * 2, G1 = w * 2 + 1;
  const int koff0 = (G0 * 8 + l8) * 64 + sw;       // K: row-major rows
  const int koff1 = (G1 * 8 + l8) * 64 + sw;
  const int voff0 = (G0 * 8 + l8) * 4096 + sw;     // V^T: hd-major rows
  const int voff1 = (G1 * 8 + l8) * 4096 + sw;
  // Q staging: 16 groups (128 rows); wave w stages groups w*4 .. w*4+3
  const int qg = w * 4;
  const int qoff0 = ((qg + 0) * 8 + l8) * 64 + sw;
  const int qoff1 = ((qg + 1) * 8 + l8) * 64 + sw;
  const int qoff2 = ((qg + 2) * 8 + l8) * 64 + sw;
  const int qoff3 = ((qg + 3) * 8 + l8) * 64 + sw;

  // fragment read offsets (shorts)
  const int c7 = c & 7;
  const int chA0 = ((q4) ^ c7) * 8;                // k-chunk t=0
  const int chA1 = ((4 + q4) ^ c7) * 8;            // k-chunk t=1
  const int rowc = c * 64;                         // K/V row = (blk*16 + c)
  const int rowq = (w * 16 + c) * 64;              // subtile a row; b = +4096
  const int pw_base = (w * 16 + c) * 64 + (q4 & 1) * 4;
  const int pw_g = q4 >> 1;

  const int b = bh >> 4, h = bh & 15;

  for (int half = 0; half < 2; ++half) {
    const int qt = half == 0 ? 31 - bx : bx;       // 128-row q-tile index
    const short* Qg = Qb + ((size_t)bh * 4096 + qt * 128) * 64;

    // prologue: stage Q(128x64) -> PL, K/V tile 0 -> buf0
    gload16(Qg + qoff0, &lds[16384 + (qg + 0) * 512]);
    gload16(Qg + qoff1, &lds[16384 + (qg + 1) * 512]);
    gload16(Qg + qoff2, &lds[16384 + (qg + 2) * 512]);
    gload16(Qg + qoff3, &lds[16384 + (qg + 3) * 512]);
    gload16(Kg + koff0, &lds[G0 * 512]);
    gload16(Kg + koff1, &lds[G1 * 512]);
    gload16(Vg + voff0, &lds[8192 + G0 * 512]);
    gload16(Vg + voff1, &lds[8192 + G1 * 512]);
    __syncthreads();

    bf16x8 qa0 = *(const bf16x8*)(PL + rowq + chA0);
    bf16x8 qa1 = *(const bf16x8*)(PL + rowq + chA1);
    bf16x8 qb0 = *(const bf16x8*)(PL + 4096 + rowq + chA0);
    bf16x8 qb1 = *(const bf16x8*)(PL + 4096 + rowq + chA1);

    f32x4 oa[4], ob[4];
#pragma unroll
    for (int i = 0; i < 4; ++i) {
      oa[i] = (f32x4){0.f, 0.f, 0.f, 0.f};
      ob[i] = (f32x4){0.f, 0.f, 0.f, 0.f};
    }
    float la = 0.f, lb = 0.f;

    const int last = 2 * qt + 1;
    for (int kt = 0; kt <= last; ++kt) {
      const int cur = (kt & 1) * 4096;
      const short* Kc = &lds[cur];
      const short* Vc = &lds[8192 + cur];
      if (kt < last) {                   // prefetch next tile (overlaps compute)
        const int nxt = ((kt + 1) & 1) * 4096;
        const short* ks = Kg + (size_t)(kt + 1) * 4096;
        const short* vs = Vg + (size_t)(kt + 1) * 64;
        gload16(ks + koff0, &lds[nxt + G0 * 512]);
        gload16(ks + koff1, &lds[nxt + G1 * 512]);
        gload16(vs + voff0, &lds[8192 + nxt + G0 * 512]);
        gload16(vs + voff1, &lds[8192 + nxt + G1 * 512]);
      }
      const bool doA = (kt <= 2 * qt);   // uniform; a skips the last kv-tile

      // S^T = K·Q^T for both subtiles from ONE K-fragment load
      f32x4 sa[4], sb[4];
#pragma unroll
      for (int ns = 0; ns < 4; ++ns) {
        bf16x8 kf0 = *(const bf16x8*)(Kc + ns * 1024 + rowc + chA0);
        bf16x8 kf1 = *(const bf16x8*)(Kc + ns * 1024 + rowc + chA1);
        sa[ns] = mfma16(kf0, qa0, (f32x4){0.f, 0.f, 0.f, 0.f});
        sa[ns] = mfma16(kf1, qa1, sa[ns]);
        sb[ns] = mfma16(kf0, qb0, (f32x4){0.f, 0.f, 0.f, 0.f});
        sb[ns] = mfma16(kf1, qb1, sb[ns]);
      }
      if (kt == 2 * qt) {                // diagonal for subtile a
#pragma unroll
        for (int ns = 0; ns < 4; ++ns)
#pragma unroll
          for (int r = 0; r < 4; ++r)
            if (ns * 16 + q4 * 4 + r > w * 16 + c) sa[ns][r] = -1e30f;
      }
      if (kt == last) {                  // diagonal for subtile b
#pragma unroll
        for (int ns = 0; ns < 4; ++ns)
#pragma unroll
          for (int r = 0; r < 4; ++r)
            if (ns * 16 + q4 * 4 + r > w * 16 + c) sb[ns][r] = -1e30f;
      }

      bf16x8 pfa0, pfa1;
      if (doA) {                         // softmax a + P_a -> PL rows 0..63
        float ps[4][4];
#pragma unroll
        for (int ns = 0; ns < 4; ++ns)
#pragma unroll
          for (int r = 0; r < 4; ++r) ps[ns][r] = fexp2(sa[ns][r]);
        float s0 = (ps[0][0] + ps[0][1]) + (ps[0][2] + ps[0][3]);
        float s1 = (ps[1][0] + ps[1][1]) + (ps[1][2] + ps[1][3]);
        float s2 = (ps[2][0] + ps[2][1]) + (ps[2][2] + ps[2][3]);
        float s3 = (ps[3][0] + ps[3][1]) + (ps[3][2] + ps[3][3]);
        float sum = (s0 + s1) + (s2 + s3);
        sum += __shfl_xor(sum, 16);
        sum += __shfl_xor(sum, 32);
        la += sum;
#pragma unroll
        for (int ns = 0; ns < 4; ++ns) {
          uint2 pk;
          pk.x = pk2bf(ps[ns][0], ps[ns][1]);
          pk.y = pk2bf(ps[ns][2], ps[ns][3]);
          *(uint2*)(PL + pw_base + (((ns * 2 + pw_g) ^ c7) * 8)) = pk;
        }
        pfa0 = *(const bf16x8*)(PL + rowq + chA0);
        pfa1 = *(const bf16x8*)(PL + rowq + chA1);
      }
      {                                  // softmax b + P_b -> PL rows 64..127
        float ps[4][4];
#pragma unroll
        for (int ns = 0; ns < 4; ++ns)
#pragma unroll
          for (int r = 0; r < 4; ++r) ps[ns][r] = fexp2(sb[ns][r]);
        float s0 = (ps[0][0] + ps[0][1]) + (ps[0][2] + ps[0][3]);
        float s1 = (ps[1][0] + ps[1][1]) + (ps[1][2] + ps[1][3]);
        float s2 = (ps[2][0] + ps[2][1]) + (ps[2][2] + ps[2][3]);
        float s3 = (ps[3][0] + ps[3][1]) + (ps[3][2] + ps[3][3]);
        float sum = (s0 + s1) + (s2 + s3);
        sum += __shfl_xor(sum, 16);
        sum += __shfl_xor(sum, 32);
        lb += sum;
#pragma unroll
        for (int ns = 0; ns < 4; ++ns) {
          uint2 pk;
          pk.x = pk2bf(ps[ns][0], ps[ns][1]);
          pk.y = pk2bf(ps[ns][2], ps[ns][3]);
          *(uint2*)(PL + 4096 + pw_base + (((ns * 2 + pw_g) ^ c7) * 8)) = pk;
        }
      }
      bf16x8 pfb0 = *(const bf16x8*)(PL + 4096 + rowq + chA0);
      bf16x8 pfb1 = *(const bf16x8*)(PL + 4096 + rowq + chA1);

      // O^T += V^T·P^T, both subtiles from ONE V-fragment load
#pragma unroll
      for (int nc = 0; nc < 4; ++nc) {
        bf16x8 vf0 = *(const bf16x8*)(Vc + nc * 1024 + rowc + chA0);
        bf16x8 vf1 = *(const bf16x8*)(Vc + nc * 1024 + rowc + chA1);
        if (doA) {
          oa[nc] = mfma16(vf0, pfa0, oa[nc]);
          oa[nc] = mfma16(vf1, pfa1, oa[nc]);
        }
        ob[nc] = mfma16(vf0, pfb0, ob[nc]);
        ob[nc] = mfma16(vf1, pfb1, ob[nc]);
      }
      __syncthreads();                   // drains prefetch; frees cur buffers
    }

    // epilogue: normalize, O^T -> PL (transpose via LDS), coalesced store
    float lia = 1.f / la, lib = 1.f / lb;
#pragma unroll
    for (int nc = 0; nc < 4; ++nc) {
      uint2 ok;
      ok.x = pk2bf(oa[nc][0] * lia, oa[nc][1] * lia);
      ok.y = pk2bf(oa[nc][2] * lia, oa[nc][3] * lia);
      *(uint2*)(PL + pw_base + (((nc * 2 + pw_g) ^ c7) * 8)) = ok;
      uint2 ok2;
      ok2.x = pk2bf(ob[nc][0] * lib, ob[nc][1] * lib);
      ok2.y = pk2bf(ob[nc][2] * lib, ob[nc][3] * lib);
      *(uint2*)(PL + 4096 + pw_base + (((nc * 2 + pw_g) ^ c7) * 8)) = ok2;
    }
    __syncthreads();
#pragma unroll
    for (int i2 = 0; i2 < 4; ++i2) {
      int ch = tid + i2 * 256;           // 1024 chunks = 128 rows x 8
      int r = ch >> 3, g2 = ch & 7;
      size_t row = (size_t)b * 4096 + qt * 128 + r;
      *(int4*)&Oaug[row * KAUG + h * 64 + g2 * 8] =
          *(const int4*)(PL + r * 64 + ((g2 ^ (r & 7)) * 8));
    }
    __syncthreads();                     // PL reads done before next half's Q
  }
}

// ---------------- host launch ------------------------------------------------
extern "C" void kernel_launch(void* const* d_in, const int* in_sizes, int n_in,
                              void* d_out, int out_size, void* d_ws, size_t ws_size,
                              hipStream_t stream) {
  const float* x   = (const float*)d_in[0];
  const float* fc  = (const float*)d_in[1];
  const float* fs  = (const float*)d_in[2];
  // d_in[3] = mask (causal, reimplemented analytically)
  const float* wq  = (const float*)d_in[4];
  const float* wqb = (const float*)d_in[5];
  const float* wk  = (const float*)d_in[6];
  const float* wv  = (const float*)d_in[7];
  const float* wo  = (const float*)d_in[8];
  const float* wob = (const float*)d_in[9];
  const float* lq1 = (const float*)d_in[10];
  const float* lq2 = (const float*)d_in[11];
  const float* lk1 = (const float*)d_in[12];
  const float* lk2 = (const float*)d_in[13];
  const float* lv1 = (const float*)d_in[14];
  const float* lv2 = (const float*)d_in[15];
  const float* lo1 = (const float*)d_in[16];
  const float* lo2 = (const float*)d_in[17];

  char* ws = (char*)d_ws;
  const size_t OFF_XAUG  = 0;
  const size_t OFF_XOAUG = 17825792;
  const size_t OFF_WQKV  = 35651584;
  const size_t OFF_WOAUG = 42336256;
  const size_t OFF_L1CAT = 44564480;
  const size_t OFF_BIASC = 44695552;
  const size_t OFF_QB    = 44707840;
  const size_t OFF_KB    = 61485056;
  const size_t OFF_VT    = 78262272;
  const size_t OFF_CS    = 95039488;   // 131072 float2 = 1 MiB

  short* xaug  = (short*)(ws + OFF_XAUG);
  short* xoaug = (short*)(ws + OFF_XOAUG);
  short* wqkv  = (short*)(ws + OFF_WQKV);
  short* woaug = (short*)(ws + OFF_WOAUG);
  short* l1cat = (short*)(ws + OFF_L1CAT);
  float* biasc = (float*)(ws + OFF_BIASC);
  short* qb    = (short*)(ws + OFF_QB);
  short* kb    = (short*)(ws + OFF_KB);
  short* vt    = (short*)(ws + OFF_VT);
  float* cs2   = (float*)(ws + OFF_CS);

  // 13044736 elements total = exactly 50956 blocks
  prep_k<<<50956, 256, 0, stream>>>(x, wq, wk, wv, wo, wqb,
                                    lq1, lq2, lk1, lk2, lv1, lv2, lo1, lo2,
                                    fc, fs,
                                    xaug, wqkv, woaug, l1cat, biasc, cs2);
  // T_qkv = x @ [lq1;lk1;lv1]^T -> xaug cols 1024..1071 (128 blocks)
  tgemm_k<3><<<128, 256, 0, stream>>>(xaug, KAUG, l1cat, 1024, 48, 1024,
                                      xaug, KAUG, 1024);
  // fused QKV projection + bias + RoPE -> qb,kb (B,H,S,HD), vt (B,H,HD,S)
  gemm_bt<2><<<dim3(24, 64), 256, 0, stream>>>(xaug, KAUG, wqkv, KAUG, 3072, KAUG,
                                               biasc, nullptr, 0, 0, qb, kb, vt,
                                               cs2);
  // flash attention -> xoaug cols 0..1023 (512 blocks, QBLK=128, paired)
  flash_k<<<dim3(16, 32), 256, 0, stream>>>(qb, kb, vt, xoaug);
  // T_o = attn_out @ lo1^T -> xoaug cols 1024..1039 (128 blocks)
  tgemm_k<1><<<128, 256, 0, stream>>>(xoaug, KAUG, l1cat + 48 * 1024, 1024,
                                      16, 1024, xoaug, KAUG, 1024);
  // final projection -> d_out (fp32)
  gemm_bt<0><<<dim3(8, 64), 256, 0, stream>>>(xoaug, KAUG, woaug, KAUG, 1024, KAUG,
                                              wob, d_out, 1024, 0,
                                              nullptr, nullptr, nullptr, nullptr);
}

// Round 8
// 389.985 us; speedup vs baseline: 1.2063x; 1.0167x over previous
//
#include <hip/hip_runtime.h>
#include <hip/hip_bf16.h>
#include <stdint.h>

// Problem constants
#define S_DIM 4096
#define D_DIM 1024
#define KAUG  1088          // 1024 + 64 (LoRA-augmented K)
#define M_ROWS 8192         // B*S

typedef short bf16x8 __attribute__((ext_vector_type(8)));
typedef float f32x4  __attribute__((ext_vector_type(4)));

__device__ __forceinline__ f32x4 mfma16(bf16x8 a, bf16x8 b, f32x4 c) {
  return __builtin_amdgcn_mfma_f32_16x16x32_bf16(a, b, c, 0, 0, 0);
}
// precise RNE (used only in memory-bound prep)
__device__ __forceinline__ short f2bs(float f) {
  __hip_bfloat16 h = __float2bfloat16(f);
  return *reinterpret_cast<short*>(&h);
}
// fast 2-op bf16 cast: +0x8000 round, take high half (<=1 ulp vs RNE on ties)
__device__ __forceinline__ short f2bs_fast(float f) {
  unsigned u = __builtin_bit_cast(unsigned, f) + 0x8000u;
  return (short)(u >> 16);
}
// fast packed pair: 2 adds + 1 v_perm_b32 (a -> low16, b -> high16)
__device__ __forceinline__ unsigned pk2bf(float a, float b) {
  unsigned ua = __builtin_bit_cast(unsigned, a) + 0x8000u;
  unsigned ub = __builtin_bit_cast(unsigned, b) + 0x8000u;
  return __builtin_amdgcn_perm(ub, ua, 0x07060302);
}
__device__ __forceinline__ float bs2f(short s) {
  __hip_bfloat16 h;
  *reinterpret_cast<short*>(&h) = s;
  return __bfloat162float(h);
}
__device__ __forceinline__ float fexp2(float x) {
  return __builtin_amdgcn_exp2f(x);   // single v_exp_f32
}
__device__ __forceinline__ void gload16(const void* g, void* l) {
  __builtin_amdgcn_global_load_lds(
      (const __attribute__((address_space(1))) unsigned int*)g,
      (__attribute__((address_space(3))) unsigned int*)l, 16, 0, 0);
}

// ---------------- prep: casts + augmented operand construction ----------------
//  R1 xaug cols 0..1023 <- bf16(x)              8388608
//  R2 wqkv_aug (3072 x 1088)                    3342336
//  R3 wo_aug  (1024 x 1088)                     1114112
//  R4 l1cat   (64 x 1024)                       65536
//  R5 bias_cat (3072)                           3072
//  R6 cs2 interleaved float2 cos/sin table      131072
__global__ void prep_k(const float* __restrict__ x,
                       const float* __restrict__ wq, const float* __restrict__ wk,
                       const float* __restrict__ wv, const float* __restrict__ wo,
                       const float* __restrict__ wqb,
                       const float* __restrict__ lq1, const float* __restrict__ lq2,
                       const float* __restrict__ lk1, const float* __restrict__ lk2,
                       const float* __restrict__ lv1, const float* __restrict__ lv2,
                       const float* __restrict__ lo1, const float* __restrict__ lo2,
                       const float* __restrict__ cf, const float* __restrict__ sf,
                       short* __restrict__ xaug, short* __restrict__ wqkv,
                       short* __restrict__ woaug, short* __restrict__ l1cat,
                       float* __restrict__ biasc, float* __restrict__ cs2)
{
  unsigned i = blockIdx.x * 256u + threadIdx.x;
  if (i < 8388608u) {   // R1: x -> bf16 into xaug cols 0..1023
    unsigned m = i >> 10, k = i & 1023u;
    xaug[(size_t)m * KAUG + k] = f2bs(x[i]);
    return;
  }
  i -= 8388608u;
  if (i < 3342336u) {   // R2: wqkv_aug (3072 x 1088)
    unsigned n = i / 1088u, k = i - n * 1088u;
    float v;
    if (k < 1024u) {
      v = (n < 1024u) ? wq[n * 1024u + k]
        : (n < 2048u) ? wk[(n - 1024u) * 1024u + k]
                      : wv[(n - 2048u) * 1024u + k];
    } else {
      unsigned r = k - 1024u, blk = r >> 4, which = n >> 10;
      if (blk == which) {
        const float* l2 = which == 0 ? lq2 : which == 1 ? lk2 : lv2;
        v = l2[(n & 1023u) * 16u + (r & 15u)];
      } else v = 0.f;
    }
    wqkv[i] = f2bs(v);
    return;
  }
  i -= 3342336u;
  if (i < 1114112u) {   // R3: wo_aug (1024 x 1088)
    unsigned n = i / 1088u, k = i - n * 1088u;
    float v = (k < 1024u) ? wo[n * 1024u + k]
            : (k < 1040u) ? lo2[n * 16u + (k - 1024u)] : 0.f;
    woaug[i] = f2bs(v);
    return;
  }
  i -= 1114112u;
  if (i < 65536u) {     // R4: l1cat (64 x 1024)
    unsigned r = i >> 10, k = i & 1023u;
    const float* src = r < 16u ? lq1 : r < 32u ? lk1 : r < 48u ? lv1 : lo1;
    l1cat[i] = f2bs(src[(r & 15u) * 1024u + k]);
    return;
  }
  i -= 65536u;
  if (i < 3072u) {      // R5: bias_cat
    biasc[i] = (i < 1024u) ? wqb[i] : 0.f;
    return;
  }
  i -= 3072u;
  if (i < 131072u) {    // R6: interleaved cos/sin
    cs2[2u * i]     = cf[i];
    cs2[2u * i + 1] = sf[i];
  }
}

// ---------------- GEMM: C[m,n] = sum_k A[m,k]*B[n,k]  (B^T layout) -----------
// XCD-AWARE BLOCK SWIZZLE (T1): without remap, linear block ids round-robin
// the 8 XCDs, so every XCD's 4MB L2 serves the WHOLE B (6.7MB for MODE 2 --
// doesn't fit) plus scattered A panels: fetch blows up to O(500MB) and the
// kernel is HBM-BW-bound (this is why r7's double-buffer was ~null: the loop
// is BW-bound, not latency-bound). Remap (requires gridDim.y == 64):
//   id = by*gridDim.x+bx; g = id&7 (XCD); j = id>>3;
//   mt = 8g + (j&7)  (per-XCD A-stripe: 2.2MB, stays L2-resident)
//   nt = j>>3        (mt-fastest order: each B panel reused by 8 adjacent
//                     blocks, streamed ~once per XCD)
// Expected fetch: MODE2 ~90-130MB (was ~0.5GB), MODE0 ~35MB (A+B L2-fit).
// 2-phase double-buffer retained (stage kt+1 before compute kt, one barrier).
// MODE 0: fp32 out + bias   MODE 1: bf16 out at [m*ldc+colofs+n]
// MODE 2: QKV scatter with FUSED RoPE on Q,K (Q also scaled by 0.125*log2e);
//         Q,K -> (B,H,S,HD); V -> transposed (B,H,HD,S) packed
template<int MODE>
__global__ __launch_bounds__(256) void gemm_bt(
    const short* __restrict__ A, int lda,
    const short* __restrict__ B, int ldb,
    int N, int K,
    const float* __restrict__ bias,
    void* __restrict__ Cout, int ldc, int colofs,
    short* __restrict__ qo, short* __restrict__ ko, short* __restrict__ vo,
    const float* __restrict__ cs2)
{
  __shared__ short As[2][128 * 32];
  __shared__ short Bs[2][128 * 32];
  const int tid = threadIdx.x;
  const int w = tid >> 6, lane = tid & 63;
  const int q4 = lane >> 4, c = lane & 15;
  const int mh = w >> 1, nh = w & 1;

  // XCD-grouped bijective remap (gridDim.y == 64 = 8 XCD x 8 mt rows)
  const int id = (int)blockIdx.y * gridDim.x + (int)blockIdx.x;
  const int g = id & 7, j = id >> 3;
  const int mt = g * 8 + (j & 7);
  const int nt = j >> 3;

  const int rl = lane >> 2;          // 0..15
  const int kc = (lane & 3) * 8;

  const short* Ag0 = A + (size_t)(mt * 128 + w * 32 + rl) * lda + kc;
  const short* Ag1 = Ag0 + (size_t)16 * lda;
  int rb0 = nt * 128 + w * 32 + rl;      if (rb0 > N - 1) rb0 = N - 1;
  int rb1 = nt * 128 + w * 32 + 16 + rl; if (rb1 > N - 1) rb1 = N - 1;
  const short* Bg0 = B + (size_t)rb0 * ldb + kc;
  const short* Bg1 = B + (size_t)rb1 * ldb + kc;
  const int sD0 = (w * 32) * 32;         // staging dest offsets (shorts)
  const int sD1 = (w * 32 + 16) * 32;

  f32x4 acc[4][4];
#pragma unroll
  for (int ms = 0; ms < 4; ++ms)
#pragma unroll
    for (int ns = 0; ns < 4; ++ns) acc[ms][ns] = (f32x4){0.f, 0.f, 0.f, 0.f};

  // prologue: tile 0 -> buf 0
  gload16(Ag0, &As[0][sD0]);
  gload16(Ag1, &As[0][sD1]);
  gload16(Bg0, &Bs[0][sD0]);
  gload16(Bg1, &Bs[0][sD1]);
  Ag0 += 32; Ag1 += 32; Bg0 += 32; Bg1 += 32;
  __syncthreads();                       // drains prologue staging

  const int nkt = K >> 5;
  for (int kt = 0; kt < nkt; ++kt) {
    const int cur = kt & 1, nxt = cur ^ 1;
    if (kt + 1 < nkt) {                  // prefetch next tile (overlaps compute)
      gload16(Ag0, &As[nxt][sD0]);
      gload16(Ag1, &As[nxt][sD1]);
      gload16(Bg0, &Bs[nxt][sD0]);
      gload16(Bg1, &Bs[nxt][sD1]);
      Ag0 += 32; Ag1 += 32; Bg0 += 32; Bg1 += 32;
    }
    bf16x8 af[4], bfr[4];
#pragma unroll
    for (int ms = 0; ms < 4; ++ms)
      af[ms] = *(const bf16x8*)&As[cur][(mh * 64 + ms * 16 + c) * 32 + q4 * 8];
#pragma unroll
    for (int ns = 0; ns < 4; ++ns)
      bfr[ns] = *(const bf16x8*)&Bs[cur][(nh * 64 + ns * 16 + c) * 32 + q4 * 8];
#pragma unroll
    for (int ms = 0; ms < 4; ++ms)
#pragma unroll
      for (int ns = 0; ns < 4; ++ns)
        acc[ms][ns] = mfma16(af[ms], bfr[ns], acc[ms][ns]);
    __syncthreads();                     // next tile staged; cur free to reuse
  }

#pragma unroll
  for (int ms = 0; ms < 4; ++ms) {
#pragma unroll
    for (int ns = 0; ns < 4; ++ns) {
      const int n = nt * 128 + nh * 64 + ns * 16 + c;
      if (MODE == 0) {
        float bsv = (n < N) ? bias[n] : 0.f;
        float* Co = (float*)Cout;
#pragma unroll
        for (int r = 0; r < 4; ++r) {
          int m = mt * 128 + mh * 64 + ms * 16 + q4 * 4 + r;
          if (n < N) Co[(size_t)m * ldc + n] = acc[ms][ns][r] + bsv;
        }
      } else if (MODE == 1) {
        short* Co = (short*)Cout;
#pragma unroll
        for (int r = 0; r < 4; ++r) {
          int m = mt * 128 + mh * 64 + ms * 16 + q4 * 4 + r;
          if (n < N) Co[(size_t)m * ldc + colofs + n] = f2bs_fast(acc[ms][ns][r]);
        }
      } else {
        float bsv = bias[n];
        int which = n >> 10;                  // wave-uniform per (nt,nh,ns)
        int m0 = mt * 128 + mh * 64 + ms * 16 + q4 * 4;
        int bb = m0 >> 12, spos = m0 & 4095;
        if (which < 2) {
          // fused RoPE: pair (even hd, odd hd) = adjacent lanes (c even/odd)
          int h = (n >> 6) & 15;
          int hd = n & 63;
          short* dst = which == 0 ? qo : ko;
          const float sgn = (c & 1) ? 1.f : -1.f;
          const int ihalf = hd >> 1;          // same for the lane pair
#pragma unroll
          for (int r = 0; r < 4; ++r) {
            float val = acc[ms][ns][r] + bsv;
            float part = __shfl_xor(val, 1);
            float2 cs = *(const float2*)&cs2[((size_t)(spos + r) * 32 + ihalf) * 2];
            // even lane: re = val*cc - part*ss ; odd lane: im = part*ss + val*cc
            float res = val * cs.x + part * (sgn * cs.y);
            if (which == 0) res *= 0.18033688011112042f;   // 0.125*log2e
            dst[(size_t)((bb * 16 + h) * 4096 + spos + r) * 64 + hd] = f2bs_fast(res);
          }
        } else {
          // V: write directly transposed (B,H,HD,S); 4 consecutive s -> 8B
          int h = (n >> 6) & 15;
          int hd = n & 63;
          uint2 vk;
          vk.x = pk2bf(acc[ms][ns][0] + bsv, acc[ms][ns][1] + bsv);
          vk.y = pk2bf(acc[ms][ns][2] + bsv, acc[ms][ns][3] + bsv);
          *(uint2*)&vo[(((size_t)bb * 16 + h) * 64 + hd) * 4096 + spos] = vk;
        }
      }
    }
  }
}

// ---------------- small-N skinny GEMM: BM=64, grid = M/64 blocks -------------
// Same 2-phase double-buffer as gemm_bt. N <= NT*16, bf16 out.
// (No swizzle: A rows are block-disjoint -- no inter-block reuse; B is 96KB,
//  L2-resident everywhere.)
template<int NT>
__global__ __launch_bounds__(256) void tgemm_k(
    const short* __restrict__ A, int lda,
    const short* __restrict__ B, int ldb,
    int N, int K, short* __restrict__ C, int ldc, int colofs)
{
  __shared__ short As[2][64 * 32];
  __shared__ short Bs[2][64 * 32];
  const int tid = threadIdx.x;
  const int w = tid >> 6, lane = tid & 63;
  const int q4 = lane >> 4, c = lane & 15;
  const int rl = lane >> 2, kc = (lane & 3) * 8;
  const int arow = w * 16 + rl;
  const int brow = arow <= N - 1 ? arow : N - 1;

  const short* Ag = A + (size_t)(blockIdx.x * 64 + arow) * lda + kc;
  const short* Bg = B + (size_t)brow * ldb + kc;
  const int sD = (w * 16) * 32;

  f32x4 acc[NT];
#pragma unroll
  for (int i = 0; i < NT; ++i) acc[i] = (f32x4){0.f, 0.f, 0.f, 0.f};

  // prologue: tile 0 -> buf 0
  gload16(Ag, &As[0][sD]);
  gload16(Bg, &Bs[0][sD]);
  Ag += 32; Bg += 32;
  __syncthreads();

  const int nkt = K >> 5;
  for (int kt = 0; kt < nkt; ++kt) {
    const int cur = kt & 1, nxt = cur ^ 1;
    if (kt + 1 < nkt) {
      gload16(Ag, &As[nxt][sD]);
      gload16(Bg, &Bs[nxt][sD]);
      Ag += 32; Bg += 32;
    }
    bf16x8 af = *(const bf16x8*)&As[cur][(w * 16 + c) * 32 + q4 * 8];
#pragma unroll
    for (int nsi = 0; nsi < NT; ++nsi) {
      bf16x8 bf = *(const bf16x8*)&Bs[cur][(nsi * 16 + c) * 32 + q4 * 8];
      acc[nsi] = mfma16(af, bf, acc[nsi]);
    }
    __syncthreads();
  }
#pragma unroll
  for (int nsi = 0; nsi < NT; ++nsi) {
#pragma unroll
    for (int r = 0; r < 4; ++r) {
      int m = blockIdx.x * 64 + w * 16 + q4 * 4 + r;
      int n = nsi * 16 + c;
      if (n < N) C[(size_t)m * ldc + colofs + n] = f2bs_fast(acc[nsi][r]);
    }
  }
}

// ---------------- Flash attention v4 (round-5/7 state, measured ~108 us) -----
// QBLK=128, paired q-tiles (31-bx, bx): uniform 68 KV-iters per block; 512
// blocks, 2/CU resident, 48KB LDS. At the ds_read_b128 issue ceiling (m134
// ~85 B/cyc): 80 b128/block-iter x 12cyc ~= the 945-cyc measured period --
// this design family's structural floor.
// ZERO-REFERENCE softmax: P = exp2(s) bounded ~2^20, f32-safe, o/l exact.
// XCD swizzle: id%8 = XCD g hosts bh in {4g..4g+3} (per-XCD K/V set = 4MB L2).
// LDS (shorts): K dbuf @0/@4096, V dbuf @8192/@12288, PL @16384 (128x64:
// Q staging, then P/O; subtile b at +4096) = 49152 B total.
__global__ __launch_bounds__(256, 2) void flash_k(
    const short* __restrict__ Qb, const short* __restrict__ Kb,
    const short* __restrict__ Vt, short* __restrict__ Oaug)
{
  __shared__ short lds[24576];
  short* const PL = &lds[16384];

  const int id = (int)blockIdx.y * 16 + (int)blockIdx.x;   // 0..511
  const int g = id & 7, j = id >> 3;                       // j in 0..63
  const int bh = g * 4 + (j >> 4);
  const int bx = j & 15;

  const int tid = threadIdx.x;
  const int w = tid >> 6, lane = tid & 63;
  const int q4 = lane >> 4, c = lane & 15;

  const short* Kg = Kb + (size_t)bh * 4096 * 64;
  const short* Vg = Vt + (size_t)bh * 64 * 4096;

  // staging source offsets (shorts), XOR-swizzled chunk layout
  const int l8 = lane >> 3, l7 = lane & 7;
  const int sw = (l7 ^ l8) * 8;
  const int G0 = w * 2, G1 = w * 2 + 1;
  const int koff0 = (G0 * 8 + l8) * 64 + sw;       // K: row-major rows
  const int koff1 = (G1 * 8 + l8) * 64 + sw;
  const int voff0 = (G0 * 8 + l8) * 4096 + sw;     // V^T: hd-major rows
  const int voff1 = (G1 * 8 + l8) * 4096 + sw;
  // Q staging: 16 groups (128 rows); wave w stages groups w*4 .. w*4+3
  const int qg = w * 4;
  const int qoff0 = ((qg + 0) * 8 + l8) * 64 + sw;
  const int qoff1 = ((qg + 1) * 8 + l8) * 64 + sw;
  const int qoff2 = ((qg + 2) * 8 + l8) * 64 + sw;
  const int qoff3 = ((qg + 3) * 8 + l8) * 64 + sw;

  // fragment read offsets (shorts)
  const int c7 = c & 7;
  const int chA0 = ((q4) ^ c7) * 8;                // k-chunk t=0
  const int chA1 = ((4 + q4) ^ c7) * 8;            // k-chunk t=1
  const int rowc = c * 64;                         // K/V row = (blk*16 + c)
  const int rowq = (w * 16 + c) * 64;              // subtile a row; b = +4096
  const int pw_base = (w * 16 + c) * 64 + (q4 & 1) * 4;
  const int pw_g = q4 >> 1;

  const int b = bh >> 4, h = bh & 15;

  for (int half = 0; half < 2; ++half) {
    const int qt = half == 0 ? 31 - bx : bx;       // 128-row q-tile index
    const short* Qg = Qb + ((size_t)bh * 4096 + qt * 128) * 64;

    // prologue: stage Q(128x64) -> PL, K/V tile 0 -> buf0
    gload16(Qg + qoff0, &lds[16384 + (qg + 0) * 512]);
    gload16(Qg + qoff1, &lds[16384 + (qg + 1) * 512]);
    gload16(Qg + qoff2, &lds[16384 + (qg + 2) * 512]);
    gload16(Qg + qoff3, &lds[16384 + (qg + 3) * 512]);
    gload16(Kg + koff0, &lds[G0 * 512]);
    gload16(Kg + koff1, &lds[G1 * 512]);
    gload16(Vg + voff0, &lds[8192 + G0 * 512]);
    gload16(Vg + voff1, &lds[8192 + G1 * 512]);
    __syncthreads();

    bf16x8 qa0 = *(const bf16x8*)(PL + rowq + chA0);
    bf16x8 qa1 = *(const bf16x8*)(PL + rowq + chA1);
    bf16x8 qb0 = *(const bf16x8*)(PL + 4096 + rowq + chA0);
    bf16x8 qb1 = *(const bf16x8*)(PL + 4096 + rowq + chA1);

    f32x4 oa[4], ob[4];
#pragma unroll
    for (int i = 0; i < 4; ++i) {
      oa[i] = (f32x4){0.f, 0.f, 0.f, 0.f};
      ob[i] = (f32x4){0.f, 0.f, 0.f, 0.f};
    }
    float la = 0.f, lb = 0.f;

    const int last = 2 * qt + 1;
    for (int kt = 0; kt <= last; ++kt) {
      const int cur = (kt & 1) * 4096;
      const short* Kc = &lds[cur];
      const short* Vc = &lds[8192 + cur];
      if (kt < last) {                   // prefetch next tile (overlaps compute)
        const int nxt = ((kt + 1) & 1) * 4096;
        const short* ks = Kg + (size_t)(kt + 1) * 4096;
        const short* vs = Vg + (size_t)(kt + 1) * 64;
        gload16(ks + koff0, &lds[nxt + G0 * 512]);
        gload16(ks + koff1, &lds[nxt + G1 * 512]);
        gload16(vs + voff0, &lds[8192 + nxt + G0 * 512]);
        gload16(vs + voff1, &lds[8192 + nxt + G1 * 512]);
      }
      const bool doA = (kt <= 2 * qt);   // uniform; a skips the last kv-tile

      // S^T = K·Q^T for both subtiles from ONE K-fragment load
      f32x4 sa[4], sb[4];
#pragma unroll
      for (int ns = 0; ns < 4; ++ns) {
        bf16x8 kf0 = *(const bf16x8*)(Kc + ns * 1024 + rowc + chA0);
        bf16x8 kf1 = *(const bf16x8*)(Kc + ns * 1024 + rowc + chA1);
        sa[ns] = mfma16(kf0, qa0, (f32x4){0.f, 0.f, 0.f, 0.f});
        sa[ns] = mfma16(kf1, qa1, sa[ns]);
        sb[ns] = mfma16(kf0, qb0, (f32x4){0.f, 0.f, 0.f, 0.f});
        sb[ns] = mfma16(kf1, qb1, sb[ns]);
      }
      if (kt == 2 * qt) {                // diagonal for subtile a
#pragma unroll
        for (int ns = 0; ns < 4; ++ns)
#pragma unroll
          for (int r = 0; r < 4; ++r)
            if (ns * 16 + q4 * 4 + r > w * 16 + c) sa[ns][r] = -1e30f;
      }
      if (kt == last) {                  // diagonal for subtile b
#pragma unroll
        for (int ns = 0; ns < 4; ++ns)
#pragma unroll
          for (int r = 0; r < 4; ++r)
            if (ns * 16 + q4 * 4 + r > w * 16 + c) sb[ns][r] = -1e30f;
      }

      bf16x8 pfa0, pfa1;
      if (doA) {                         // softmax a + P_a -> PL rows 0..63
        float ps[4][4];
#pragma unroll
        for (int ns = 0; ns < 4; ++ns)
#pragma unroll
          for (int r = 0; r < 4; ++r) ps[ns][r] = fexp2(sa[ns][r]);
        float s0 = (ps[0][0] + ps[0][1]) + (ps[0][2] + ps[0][3]);
        float s1 = (ps[1][0] + ps[1][1]) + (ps[1][2] + ps[1][3]);
        float s2 = (ps[2][0] + ps[2][1]) + (ps[2][2] + ps[2][3]);
        float s3 = (ps[3][0] + ps[3][1]) + (ps[3][2] + ps[3][3]);
        float sum = (s0 + s1) + (s2 + s3);
        sum += __shfl_xor(sum, 16);
        sum += __shfl_xor(sum, 32);
        la += sum;
#pragma unroll
        for (int ns = 0; ns < 4; ++ns) {
          uint2 pk;
          pk.x = pk2bf(ps[ns][0], ps[ns][1]);
          pk.y = pk2bf(ps[ns][2], ps[ns][3]);
          *(uint2*)(PL + pw_base + (((ns * 2 + pw_g) ^ c7) * 8)) = pk;
        }
        pfa0 = *(const bf16x8*)(PL + rowq + chA0);
        pfa1 = *(const bf16x8*)(PL + rowq + chA1);
      }
      {                                  // softmax b + P_b -> PL rows 64..127
        float ps[4][4];
#pragma unroll
        for (int ns = 0; ns < 4; ++ns)
#pragma unroll
          for (int r = 0; r < 4; ++r) ps[ns][r] = fexp2(sb[ns][r]);
        float s0 = (ps[0][0] + ps[0][1]) + (ps[0][2] + ps[0][3]);
        float s1 = (ps[1][0] + ps[1][1]) + (ps[1][2] + ps[1][3]);
        float s2 = (ps[2][0] + ps[2][1]) + (ps[2][2] + ps[2][3]);
        float s3 = (ps[3][0] + ps[3][1]) + (ps[3][2] + ps[3][3]);
        float sum = (s0 + s1) + (s2 + s3);
        sum += __shfl_xor(sum, 16);
        sum += __shfl_xor(sum, 32);
        lb += sum;
#pragma unroll
        for (int ns = 0; ns < 4; ++ns) {
          uint2 pk;
          pk.x = pk2bf(ps[ns][0], ps[ns][1]);
          pk.y = pk2bf(ps[ns][2], ps[ns][3]);
          *(uint2*)(PL + 4096 + pw_base + (((ns * 2 + pw_g) ^ c7) * 8)) = pk;
        }
      }
      bf16x8 pfb0 = *(const bf16x8*)(PL + 4096 + rowq + chA0);
      bf16x8 pfb1 = *(const bf16x8*)(PL + 4096 + rowq + chA1);

      // O^T += V^T·P^T, both subtiles from ONE V-fragment load
#pragma unroll
      for (int nc = 0; nc < 4; ++nc) {
        bf16x8 vf0 = *(const bf16x8*)(Vc + nc * 1024 + rowc + chA0);
        bf16x8 vf1 = *(const bf16x8*)(Vc + nc * 1024 + rowc + chA1);
        if (doA) {
          oa[nc] = mfma16(vf0, pfa0, oa[nc]);
          oa[nc] = mfma16(vf1, pfa1, oa[nc]);
        }
        ob[nc] = mfma16(vf0, pfb0, ob[nc]);
        ob[nc] = mfma16(vf1, pfb1, ob[nc]);
      }
      __syncthreads();                   // drains prefetch; frees cur buffers
    }

    // epilogue: normalize, O^T -> PL (transpose via LDS), coalesced store
    float lia = 1.f / la, lib = 1.f / lb;
#pragma unroll
    for (int nc = 0; nc < 4; ++nc) {
      uint2 ok;
      ok.x = pk2bf(oa[nc][0] * lia, oa[nc][1] * lia);
      ok.y = pk2bf(oa[nc][2] * lia, oa[nc][3] * lia);
      *(uint2*)(PL + pw_base + (((nc * 2 + pw_g) ^ c7) * 8)) = ok;
      uint2 ok2;
      ok2.x = pk2bf(ob[nc][0] * lib, ob[nc][1] * lib);
      ok2.y = pk2bf(ob[nc][2] * lib, ob[nc][3] * lib);
      *(uint2*)(PL + 4096 + pw_base + (((nc * 2 + pw_g) ^ c7) * 8)) = ok2;
    }
    __syncthreads();
#pragma unroll
    for (int i2 = 0; i2 < 4; ++i2) {
      int ch = tid + i2 * 256;           // 1024 chunks = 128 rows x 8
      int r = ch >> 3, g2 = ch & 7;
      size_t row = (size_t)b * 4096 + qt * 128 + r;
      *(int4*)&Oaug[row * KAUG + h * 64 + g2 * 8] =
          *(const int4*)(PL + r * 64 + ((g2 ^ (r & 7)) * 8));
    }
    __syncthreads();                     // PL reads done before next half's Q
  }
}

// ---------------- host launch ------------------------------------------------
extern "C" void kernel_launch(void* const* d_in, const int* in_sizes, int n_in,
                              void* d_out, int out_size, void* d_ws, size_t ws_size,
                              hipStream_t stream) {
  const float* x   = (const float*)d_in[0];
  const float* fc  = (const float*)d_in[1];
  const float* fs  = (const float*)d_in[2];
  // d_in[3] = mask (causal, reimplemented analytically)
  const float* wq  = (const float*)d_in[4];
  const float* wqb = (const float*)d_in[5];
  const float* wk  = (const float*)d_in[6];
  const float* wv  = (const float*)d_in[7];
  const float* wo  = (const float*)d_in[8];
  const float* wob = (const float*)d_in[9];
  const float* lq1 = (const float*)d_in[10];
  const float* lq2 = (const float*)d_in[11];
  const float* lk1 = (const float*)d_in[12];
  const float* lk2 = (const float*)d_in[13];
  const float* lv1 = (const float*)d_in[14];
  const float* lv2 = (const float*)d_in[15];
  const float* lo1 = (const float*)d_in[16];
  const float* lo2 = (const float*)d_in[17];

  char* ws = (char*)d_ws;
  const size_t OFF_XAUG  = 0;
  const size_t OFF_XOAUG = 17825792;
  const size_t OFF_WQKV  = 35651584;
  const size_t OFF_WOAUG = 42336256;
  const size_t OFF_L1CAT = 44564480;
  const size_t OFF_BIASC = 44695552;
  const size_t OFF_QB    = 44707840;
  const size_t OFF_KB    = 61485056;
  const size_t OFF_VT    = 78262272;
  const size_t OFF_CS    = 95039488;   // 131072 float2 = 1 MiB

  short* xaug  = (short*)(ws + OFF_XAUG);
  short* xoaug = (short*)(ws + OFF_XOAUG);
  short* wqkv  = (short*)(ws + OFF_WQKV);
  short* woaug = (short*)(ws + OFF_WOAUG);
  short* l1cat = (short*)(ws + OFF_L1CAT);
  float* biasc = (float*)(ws + OFF_BIASC);
  short* qb    = (short*)(ws + OFF_QB);
  short* kb    = (short*)(ws + OFF_KB);
  short* vt    = (short*)(ws + OFF_VT);
  float* cs2   = (float*)(ws + OFF_CS);

  // 13044736 elements total = exactly 50956 blocks
  prep_k<<<50956, 256, 0, stream>>>(x, wq, wk, wv, wo, wqb,
                                    lq1, lq2, lk1, lk2, lv1, lv2, lo1, lo2,
                                    fc, fs,
                                    xaug, wqkv, woaug, l1cat, biasc, cs2);
  // T_qkv = x @ [lq1;lk1;lv1]^T -> xaug cols 1024..1071 (128 blocks)
  tgemm_k<3><<<128, 256, 0, stream>>>(xaug, KAUG, l1cat, 1024, 48, 1024,
                                      xaug, KAUG, 1024);
  // fused QKV projection + bias + RoPE -> qb,kb (B,H,S,HD), vt (B,H,HD,S)
  gemm_bt<2><<<dim3(24, 64), 256, 0, stream>>>(xaug, KAUG, wqkv, KAUG, 3072, KAUG,
                                               biasc, nullptr, 0, 0, qb, kb, vt,
                                               cs2);
  // flash attention -> xoaug cols 0..1023 (512 blocks, QBLK=128, paired)
  flash_k<<<dim3(16, 32), 256, 0, stream>>>(qb, kb, vt, xoaug);
  // T_o = attn_out @ lo1^T -> xoaug cols 1024..1039 (128 blocks)
  tgemm_k<1><<<128, 256, 0, stream>>>(xoaug, KAUG, l1cat + 48 * 1024, 1024,
                                      16, 1024, xoaug, KAUG, 1024);
  // final projection -> d_out (fp32)
  gemm_bt<0><<<dim3(8, 64), 256, 0, stream>>>(xoaug, KAUG, woaug, KAUG, 1024, KAUG,
                                              wob, d_out, 1024, 0,
                                              nullptr, nullptr, nullptr, nullptr);
}

// Round 9
// 365.421 us; speedup vs baseline: 1.2874x; 1.0672x over previous
//
#include <hip/hip_runtime.h>
#include <hip/hip_bf16.h>
#include <stdint.h>

// Problem constants
#define S_DIM 4096
#define D_DIM 1024
#define M_ROWS 8192         // B*S

typedef short bf16x8 __attribute__((ext_vector_type(8)));
typedef float f32x4  __attribute__((ext_vector_type(4)));

__device__ __forceinline__ f32x4 mfma16(bf16x8 a, bf16x8 b, f32x4 c) {
  return __builtin_amdgcn_mfma_f32_16x16x32_bf16(a, b, c, 0, 0, 0);
}
// precise RNE (used only in memory-bound prep)
__device__ __forceinline__ short f2bs(float f) {
  __hip_bfloat16 h = __float2bfloat16(f);
  return *reinterpret_cast<short*>(&h);
}
// fast 2-op bf16 cast: +0x8000 round, take high half (<=1 ulp vs RNE on ties)
__device__ __forceinline__ short f2bs_fast(float f) {
  unsigned u = __builtin_bit_cast(unsigned, f) + 0x8000u;
  return (short)(u >> 16);
}
// fast packed pair: 2 adds + 1 v_perm_b32 (a -> low16, b -> high16)
__device__ __forceinline__ unsigned pk2bf(float a, float b) {
  unsigned ua = __builtin_bit_cast(unsigned, a) + 0x8000u;
  unsigned ub = __builtin_bit_cast(unsigned, b) + 0x8000u;
  return __builtin_amdgcn_perm(ub, ua, 0x07060302);
}
__device__ __forceinline__ float fexp2(float x) {
  return __builtin_amdgcn_exp2f(x);   // single v_exp_f32
}
__device__ __forceinline__ void gload16(const void* g, void* l) {
  __builtin_amdgcn_global_load_lds(
      (const __attribute__((address_space(1))) unsigned int*)g,
      (__attribute__((address_space(3))) unsigned int*)l, 16, 0, 0);
}

// ---------------- prep: LoRA folded into EFFECTIVE WEIGHTS -------------------
// x@w^T + x@l1^T@l2^T == x@(w + l2@l1)^T  -- rank-16 update, 16 FMA/element,
// fp32 accumulate then one RNE cast (removes the old bf16-T double rounding).
// Eliminates both tgemm passes and the 1088-col augmentation (K = 1024).
//  R1 xaug <- bf16(x)                       8388608
//  R2 wqkv_eff (3072 x 1024)                3145728
//  R3 wo_eff  (1024 x 1024)                 1048576
//  R5 bias_cat (3072)                       3072
//  R6 cs2 interleaved float2 cos/sin        131072
//  total 12717056 = exactly 49676 blocks
__global__ void prep_k(const float* __restrict__ x,
                       const float* __restrict__ wq, const float* __restrict__ wk,
                       const float* __restrict__ wv, const float* __restrict__ wo,
                       const float* __restrict__ wqb,
                       const float* __restrict__ lq1, const float* __restrict__ lq2,
                       const float* __restrict__ lk1, const float* __restrict__ lk2,
                       const float* __restrict__ lv1, const float* __restrict__ lv2,
                       const float* __restrict__ lo1, const float* __restrict__ lo2,
                       const float* __restrict__ cf, const float* __restrict__ sf,
                       short* __restrict__ xaug, short* __restrict__ wqkv,
                       short* __restrict__ woeff,
                       float* __restrict__ biasc, float* __restrict__ cs2)
{
  unsigned i = blockIdx.x * 256u + threadIdx.x;
  if (i < 8388608u) {   // R1: x -> bf16 (plain stride-1024 layout)
    xaug[i] = f2bs(x[i]);
    return;
  }
  i -= 8388608u;
  if (i < 3145728u) {   // R2: wqkv_eff = w + l2@l1 (rank-16 update, fp32)
    unsigned n = i >> 10, k = i & 1023u;
    const float *wsrc, *l1, *l2;
    unsigned nn;
    if (n < 1024u)      { wsrc = wq; l1 = lq1; l2 = lq2; nn = n; }
    else if (n < 2048u) { wsrc = wk; l1 = lk1; l2 = lk2; nn = n - 1024u; }
    else                { wsrc = wv; l1 = lv1; l2 = lv2; nn = n - 2048u; }
    float v = wsrc[nn * 1024u + k];
#pragma unroll
    for (unsigned r = 0; r < 16u; ++r)
      v += l2[nn * 16u + r] * l1[r * 1024u + k];
    wqkv[i] = f2bs(v);
    return;
  }
  i -= 3145728u;
  if (i < 1048576u) {   // R3: wo_eff = wo + lo2@lo1
    unsigned n = i >> 10, k = i & 1023u;
    float v = wo[i];
#pragma unroll
    for (unsigned r = 0; r < 16u; ++r)
      v += lo2[n * 16u + r] * lo1[r * 1024u + k];
    woeff[i] = f2bs(v);
    return;
  }
  i -= 1048576u;
  if (i < 3072u) {      // R5: bias_cat
    biasc[i] = (i < 1024u) ? wqb[i] : 0.f;
    return;
  }
  i -= 3072u;
  if (i < 131072u) {    // R6: interleaved cos/sin
    cs2[2u * i]     = cf[i];
    cs2[2u * i + 1] = sf[i];
  }
}

// ---------------- GEMM: C[m,n] = sum_k A[m,k]*B[n,k]  (B^T layout) -----------
// XCD-AWARE BLOCK SWIZZLE (T1, requires gridDim.y == 64):
//   id = by*gridDim.x+bx; g = id&7 (XCD); j = id>>3;
//   mt = 8g + (j&7)  (per-XCD A-stripe stays L2-resident)
//   nt = j>>3        (mt-fastest: each B panel reused by 8 adjacent blocks)
// 2-phase double-buffer: stage tile kt+1 into buf^1 BEFORE computing tile kt;
// one vmcnt-draining barrier per K-step.
// MODE 0: fp32 out + bias   MODE 1: bf16 out at [m*ldc+colofs+n]
// MODE 2: QKV scatter with FUSED RoPE on Q,K (Q also scaled by 0.125*log2e);
//         Q,K -> (B,H,S,HD); V -> transposed (B,H,HD,S) packed
template<int MODE>
__global__ __launch_bounds__(256) void gemm_bt(
    const short* __restrict__ A, int lda,
    const short* __restrict__ B, int ldb,
    int N, int K,
    const float* __restrict__ bias,
    void* __restrict__ Cout, int ldc, int colofs,
    short* __restrict__ qo, short* __restrict__ ko, short* __restrict__ vo,
    const float* __restrict__ cs2)
{
  __shared__ short As[2][128 * 32];
  __shared__ short Bs[2][128 * 32];
  const int tid = threadIdx.x;
  const int w = tid >> 6, lane = tid & 63;
  const int q4 = lane >> 4, c = lane & 15;
  const int mh = w >> 1, nh = w & 1;

  // XCD-grouped bijective remap (gridDim.y == 64 = 8 XCD x 8 mt rows)
  const int id = (int)blockIdx.y * gridDim.x + (int)blockIdx.x;
  const int g = id & 7, j = id >> 3;
  const int mt = g * 8 + (j & 7);
  const int nt = j >> 3;

  const int rl = lane >> 2;          // 0..15
  const int kc = (lane & 3) * 8;

  const short* Ag0 = A + (size_t)(mt * 128 + w * 32 + rl) * lda + kc;
  const short* Ag1 = Ag0 + (size_t)16 * lda;
  int rb0 = nt * 128 + w * 32 + rl;      if (rb0 > N - 1) rb0 = N - 1;
  int rb1 = nt * 128 + w * 32 + 16 + rl; if (rb1 > N - 1) rb1 = N - 1;
  const short* Bg0 = B + (size_t)rb0 * ldb + kc;
  const short* Bg1 = B + (size_t)rb1 * ldb + kc;
  const int sD0 = (w * 32) * 32;         // staging dest offsets (shorts)
  const int sD1 = (w * 32 + 16) * 32;

  f32x4 acc[4][4];
#pragma unroll
  for (int ms = 0; ms < 4; ++ms)
#pragma unroll
    for (int ns = 0; ns < 4; ++ns) acc[ms][ns] = (f32x4){0.f, 0.f, 0.f, 0.f};

  // prologue: tile 0 -> buf 0
  gload16(Ag0, &As[0][sD0]);
  gload16(Ag1, &As[0][sD1]);
  gload16(Bg0, &Bs[0][sD0]);
  gload16(Bg1, &Bs[0][sD1]);
  Ag0 += 32; Ag1 += 32; Bg0 += 32; Bg1 += 32;
  __syncthreads();                       // drains prologue staging

  const int nkt = K >> 5;
  for (int kt = 0; kt < nkt; ++kt) {
    const int cur = kt & 1, nxt = cur ^ 1;
    if (kt + 1 < nkt) {                  // prefetch next tile (overlaps compute)
      gload16(Ag0, &As[nxt][sD0]);
      gload16(Ag1, &As[nxt][sD1]);
      gload16(Bg0, &Bs[nxt][sD0]);
      gload16(Bg1, &Bs[nxt][sD1]);
      Ag0 += 32; Ag1 += 32; Bg0 += 32; Bg1 += 32;
    }
    bf16x8 af[4], bfr[4];
#pragma unroll
    for (int ms = 0; ms < 4; ++ms)
      af[ms] = *(const bf16x8*)&As[cur][(mh * 64 + ms * 16 + c) * 32 + q4 * 8];
#pragma unroll
    for (int ns = 0; ns < 4; ++ns)
      bfr[ns] = *(const bf16x8*)&Bs[cur][(nh * 64 + ns * 16 + c) * 32 + q4 * 8];
#pragma unroll
    for (int ms = 0; ms < 4; ++ms)
#pragma unroll
      for (int ns = 0; ns < 4; ++ns)
        acc[ms][ns] = mfma16(af[ms], bfr[ns], acc[ms][ns]);
    __syncthreads();                     // next tile staged; cur free to reuse
  }

#pragma unroll
  for (int ms = 0; ms < 4; ++ms) {
#pragma unroll
    for (int ns = 0; ns < 4; ++ns) {
      const int n = nt * 128 + nh * 64 + ns * 16 + c;
      if (MODE == 0) {
        float bsv = (n < N) ? bias[n] : 0.f;
        float* Co = (float*)Cout;
#pragma unroll
        for (int r = 0; r < 4; ++r) {
          int m = mt * 128 + mh * 64 + ms * 16 + q4 * 4 + r;
          if (n < N) Co[(size_t)m * ldc + n] = acc[ms][ns][r] + bsv;
        }
      } else if (MODE == 1) {
        short* Co = (short*)Cout;
#pragma unroll
        for (int r = 0; r < 4; ++r) {
          int m = mt * 128 + mh * 64 + ms * 16 + q4 * 4 + r;
          if (n < N) Co[(size_t)m * ldc + colofs + n] = f2bs_fast(acc[ms][ns][r]);
        }
      } else {
        float bsv = bias[n];
        int which = n >> 10;                  // wave-uniform per (nt,nh,ns)
        int m0 = mt * 128 + mh * 64 + ms * 16 + q4 * 4;
        int bb = m0 >> 12, spos = m0 & 4095;
        if (which < 2) {
          // fused RoPE: pair (even hd, odd hd) = adjacent lanes (c even/odd)
          int h = (n >> 6) & 15;
          int hd = n & 63;
          short* dst = which == 0 ? qo : ko;
          const float sgn = (c & 1) ? 1.f : -1.f;
          const int ihalf = hd >> 1;          // same for the lane pair
#pragma unroll
          for (int r = 0; r < 4; ++r) {
            float val = acc[ms][ns][r] + bsv;
            float part = __shfl_xor(val, 1);
            float2 cs = *(const float2*)&cs2[((size_t)(spos + r) * 32 + ihalf) * 2];
            // even lane: re = val*cc - part*ss ; odd lane: im = part*ss + val*cc
            float res = val * cs.x + part * (sgn * cs.y);
            if (which == 0) res *= 0.18033688011112042f;   // 0.125*log2e
            dst[(size_t)((bb * 16 + h) * 4096 + spos + r) * 64 + hd] = f2bs_fast(res);
          }
        } else {
          // V: write directly transposed (B,H,HD,S); 4 consecutive s -> 8B
          int h = (n >> 6) & 15;
          int hd = n & 63;
          uint2 vk;
          vk.x = pk2bf(acc[ms][ns][0] + bsv, acc[ms][ns][1] + bsv);
          vk.y = pk2bf(acc[ms][ns][2] + bsv, acc[ms][ns][3] + bsv);
          *(uint2*)&vo[(((size_t)bb * 16 + h) * 64 + hd) * 4096 + spos] = vk;
        }
      }
    }
  }
}

// ---------------- Flash attention v4 (round-5/7 state, measured ~107 us) -----
// QBLK=128, paired q-tiles (31-bx, bx): uniform 68 KV-iters per block; 512
// blocks, 2/CU resident, 48KB LDS. At the ds_read_b128 issue ceiling (m134
// ~85 B/cyc) -- this design family's structural floor.
// ZERO-REFERENCE softmax: P = exp2(s) bounded ~2^20, f32-safe, o/l exact.
// XCD swizzle: id%8 = XCD g hosts bh in {4g..4g+3} (per-XCD K/V set = 4MB L2).
// LDS (shorts): K dbuf @0/@4096, V dbuf @8192/@12288, PL @16384 (128x64:
// Q staging, then P/O; subtile b at +4096) = 49152 B total.
// Output xoaug is now plain stride-1024 (augmentation removed).
__global__ __launch_bounds__(256, 2) void flash_k(
    const short* __restrict__ Qb, const short* __restrict__ Kb,
    const short* __restrict__ Vt, short* __restrict__ Oaug)
{
  __shared__ short lds[24576];
  short* const PL = &lds[16384];

  const int id = (int)blockIdx.y * 16 + (int)blockIdx.x;   // 0..511
  const int g = id & 7, j = id >> 3;                       // j in 0..63
  const int bh = g * 4 + (j >> 4);
  const int bx = j & 15;

  const int tid = threadIdx.x;
  const int w = tid >> 6, lane = tid & 63;
  const int q4 = lane >> 4, c = lane & 15;

  const short* Kg = Kb + (size_t)bh * 4096 * 64;
  const short* Vg = Vt + (size_t)bh * 64 * 4096;

  // staging source offsets (shorts), XOR-swizzled chunk layout
  const int l8 = lane >> 3, l7 = lane & 7;
  const int sw = (l7 ^ l8) * 8;
  const int G0 = w * 2, G1 = w * 2 + 1;
  const int koff0 = (G0 * 8 + l8) * 64 + sw;       // K: row-major rows
  const int koff1 = (G1 * 8 + l8) * 64 + sw;
  const int voff0 = (G0 * 8 + l8) * 4096 + sw;     // V^T: hd-major rows
  const int voff1 = (G1 * 8 + l8) * 4096 + sw;
  // Q staging: 16 groups (128 rows); wave w stages groups w*4 .. w*4+3
  const int qg = w * 4;
  const int qoff0 = ((qg + 0) * 8 + l8) * 64 + sw;
  const int qoff1 = ((qg + 1) * 8 + l8) * 64 + sw;
  const int qoff2 = ((qg + 2) * 8 + l8) * 64 + sw;
  const int qoff3 = ((qg + 3) * 8 + l8) * 64 + sw;

  // fragment read offsets (shorts)
  const int c7 = c & 7;
  const int chA0 = ((q4) ^ c7) * 8;                // k-chunk t=0
  const int chA1 = ((4 + q4) ^ c7) * 8;            // k-chunk t=1
  const int rowc = c * 64;                         // K/V row = (blk*16 + c)
  const int rowq = (w * 16 + c) * 64;              // subtile a row; b = +4096
  const int pw_base = (w * 16 + c) * 64 + (q4 & 1) * 4;
  const int pw_g = q4 >> 1;

  const int b = bh >> 4, h = bh & 15;

  for (int half = 0; half < 2; ++half) {
    const int qt = half == 0 ? 31 - bx : bx;       // 128-row q-tile index
    const short* Qg = Qb + ((size_t)bh * 4096 + qt * 128) * 64;

    // prologue: stage Q(128x64) -> PL, K/V tile 0 -> buf0
    gload16(Qg + qoff0, &lds[16384 + (qg + 0) * 512]);
    gload16(Qg + qoff1, &lds[16384 + (qg + 1) * 512]);
    gload16(Qg + qoff2, &lds[16384 + (qg + 2) * 512]);
    gload16(Qg + qoff3, &lds[16384 + (qg + 3) * 512]);
    gload16(Kg + koff0, &lds[G0 * 512]);
    gload16(Kg + koff1, &lds[G1 * 512]);
    gload16(Vg + voff0, &lds[8192 + G0 * 512]);
    gload16(Vg + voff1, &lds[8192 + G1 * 512]);
    __syncthreads();

    bf16x8 qa0 = *(const bf16x8*)(PL + rowq + chA0);
    bf16x8 qa1 = *(const bf16x8*)(PL + rowq + chA1);
    bf16x8 qb0 = *(const bf16x8*)(PL + 4096 + rowq + chA0);
    bf16x8 qb1 = *(const bf16x8*)(PL + 4096 + rowq + chA1);

    f32x4 oa[4], ob[4];
#pragma unroll
    for (int i = 0; i < 4; ++i) {
      oa[i] = (f32x4){0.f, 0.f, 0.f, 0.f};
      ob[i] = (f32x4){0.f, 0.f, 0.f, 0.f};
    }
    float la = 0.f, lb = 0.f;

    const int last = 2 * qt + 1;
    for (int kt = 0; kt <= last; ++kt) {
      const int cur = (kt & 1) * 4096;
      const short* Kc = &lds[cur];
      const short* Vc = &lds[8192 + cur];
      if (kt < last) {                   // prefetch next tile (overlaps compute)
        const int nxt = ((kt + 1) & 1) * 4096;
        const short* ks = Kg + (size_t)(kt + 1) * 4096;
        const short* vs = Vg + (size_t)(kt + 1) * 64;
        gload16(ks + koff0, &lds[nxt + G0 * 512]);
        gload16(ks + koff1, &lds[nxt + G1 * 512]);
        gload16(vs + voff0, &lds[8192 + nxt + G0 * 512]);
        gload16(vs + voff1, &lds[8192 + nxt + G1 * 512]);
      }
      const bool doA = (kt <= 2 * qt);   // uniform; a skips the last kv-tile

      // S^T = K·Q^T for both subtiles from ONE K-fragment load
      f32x4 sa[4], sb[4];
#pragma unroll
      for (int ns = 0; ns < 4; ++ns) {
        bf16x8 kf0 = *(const bf16x8*)(Kc + ns * 1024 + rowc + chA0);
        bf16x8 kf1 = *(const bf16x8*)(Kc + ns * 1024 + rowc + chA1);
        sa[ns] = mfma16(kf0, qa0, (f32x4){0.f, 0.f, 0.f, 0.f});
        sa[ns] = mfma16(kf1, qa1, sa[ns]);
        sb[ns] = mfma16(kf0, qb0, (f32x4){0.f, 0.f, 0.f, 0.f});
        sb[ns] = mfma16(kf1, qb1, sb[ns]);
      }
      if (kt == 2 * qt) {                // diagonal for subtile a
#pragma unroll
        for (int ns = 0; ns < 4; ++ns)
#pragma unroll
          for (int r = 0; r < 4; ++r)
            if (ns * 16 + q4 * 4 + r > w * 16 + c) sa[ns][r] = -1e30f;
      }
      if (kt == last) {                  // diagonal for subtile b
#pragma unroll
        for (int ns = 0; ns < 4; ++ns)
#pragma unroll
          for (int r = 0; r < 4; ++r)
            if (ns * 16 + q4 * 4 + r > w * 16 + c) sb[ns][r] = -1e30f;
      }

      bf16x8 pfa0, pfa1;
      if (doA) {                         // softmax a + P_a -> PL rows 0..63
        float ps[4][4];
#pragma unroll
        for (int ns = 0; ns < 4; ++ns)
#pragma unroll
          for (int r = 0; r < 4; ++r) ps[ns][r] = fexp2(sa[ns][r]);
        float s0 = (ps[0][0] + ps[0][1]) + (ps[0][2] + ps[0][3]);
        float s1 = (ps[1][0] + ps[1][1]) + (ps[1][2] + ps[1][3]);
        float s2 = (ps[2][0] + ps[2][1]) + (ps[2][2] + ps[2][3]);
        float s3 = (ps[3][0] + ps[3][1]) + (ps[3][2] + ps[3][3]);
        float sum = (s0 + s1) + (s2 + s3);
        sum += __shfl_xor(sum, 16);
        sum += __shfl_xor(sum, 32);
        la += sum;
#pragma unroll
        for (int ns = 0; ns < 4; ++ns) {
          uint2 pk;
          pk.x = pk2bf(ps[ns][0], ps[ns][1]);
          pk.y = pk2bf(ps[ns][2], ps[ns][3]);
          *(uint2*)(PL + pw_base + (((ns * 2 + pw_g) ^ c7) * 8)) = pk;
        }
        pfa0 = *(const bf16x8*)(PL + rowq + chA0);
        pfa1 = *(const bf16x8*)(PL + rowq + chA1);
      }
      {                                  // softmax b + P_b -> PL rows 64..127
        float ps[4][4];
#pragma unroll
        for (int ns = 0; ns < 4; ++ns)
#pragma unroll
          for (int r = 0; r < 4; ++r) ps[ns][r] = fexp2(sb[ns][r]);
        float s0 = (ps[0][0] + ps[0][1]) + (ps[0][2] + ps[0][3]);
        float s1 = (ps[1][0] + ps[1][1]) + (ps[1][2] + ps[1][3]);
        float s2 = (ps[2][0] + ps[2][1]) + (ps[2][2] + ps[2][3]);
        float s3 = (ps[3][0] + ps[3][1]) + (ps[3][2] + ps[3][3]);
        float sum = (s0 + s1) + (s2 + s3);
        sum += __shfl_xor(sum, 16);
        sum += __shfl_xor(sum, 32);
        lb += sum;
#pragma unroll
        for (int ns = 0; ns < 4; ++ns) {
          uint2 pk;
          pk.x = pk2bf(ps[ns][0], ps[ns][1]);
          pk.y = pk2bf(ps[ns][2], ps[ns][3]);
          *(uint2*)(PL + 4096 + pw_base + (((ns * 2 + pw_g) ^ c7) * 8)) = pk;
        }
      }
      bf16x8 pfb0 = *(const bf16x8*)(PL + 4096 + rowq + chA0);
      bf16x8 pfb1 = *(const bf16x8*)(PL + 4096 + rowq + chA1);

      // O^T += V^T·P^T, both subtiles from ONE V-fragment load
#pragma unroll
      for (int nc = 0; nc < 4; ++nc) {
        bf16x8 vf0 = *(const bf16x8*)(Vc + nc * 1024 + rowc + chA0);
        bf16x8 vf1 = *(const bf16x8*)(Vc + nc * 1024 + rowc + chA1);
        if (doA) {
          oa[nc] = mfma16(vf0, pfa0, oa[nc]);
          oa[nc] = mfma16(vf1, pfa1, oa[nc]);
        }
        ob[nc] = mfma16(vf0, pfb0, ob[nc]);
        ob[nc] = mfma16(vf1, pfb1, ob[nc]);
      }
      __syncthreads();                   // drains prefetch; frees cur buffers
    }

    // epilogue: normalize, O^T -> PL (transpose via LDS), coalesced store
    float lia = 1.f / la, lib = 1.f / lb;
#pragma unroll
    for (int nc = 0; nc < 4; ++nc) {
      uint2 ok;
      ok.x = pk2bf(oa[nc][0] * lia, oa[nc][1] * lia);
      ok.y = pk2bf(oa[nc][2] * lia, oa[nc][3] * lia);
      *(uint2*)(PL + pw_base + (((nc * 2 + pw_g) ^ c7) * 8)) = ok;
      uint2 ok2;
      ok2.x = pk2bf(ob[nc][0] * lib, ob[nc][1] * lib);
      ok2.y = pk2bf(ob[nc][2] * lib, ob[nc][3] * lib);
      *(uint2*)(PL + 4096 + pw_base + (((nc * 2 + pw_g) ^ c7) * 8)) = ok2;
    }
    __syncthreads();
#pragma unroll
    for (int i2 = 0; i2 < 4; ++i2) {
      int ch = tid + i2 * 256;           // 1024 chunks = 128 rows x 8
      int r = ch >> 3, g2 = ch & 7;
      size_t row = (size_t)b * 4096 + qt * 128 + r;
      *(int4*)&Oaug[row * 1024 + h * 64 + g2 * 8] =
          *(const int4*)(PL + r * 64 + ((g2 ^ (r & 7)) * 8));
    }
    __syncthreads();                     // PL reads done before next half's Q
  }
}

// ---------------- host launch ------------------------------------------------
extern "C" void kernel_launch(void* const* d_in, const int* in_sizes, int n_in,
                              void* d_out, int out_size, void* d_ws, size_t ws_size,
                              hipStream_t stream) {
  const float* x   = (const float*)d_in[0];
  const float* fc  = (const float*)d_in[1];
  const float* fs  = (const float*)d_in[2];
  // d_in[3] = mask (causal, reimplemented analytically)
  const float* wq  = (const float*)d_in[4];
  const float* wqb = (const float*)d_in[5];
  const float* wk  = (const float*)d_in[6];
  const float* wv  = (const float*)d_in[7];
  const float* wo  = (const float*)d_in[8];
  const float* wob = (const float*)d_in[9];
  const float* lq1 = (const float*)d_in[10];
  const float* lq2 = (const float*)d_in[11];
  const float* lk1 = (const float*)d_in[12];
  const float* lk2 = (const float*)d_in[13];
  const float* lv1 = (const float*)d_in[14];
  const float* lv2 = (const float*)d_in[15];
  const float* lo1 = (const float*)d_in[16];
  const float* lo2 = (const float*)d_in[17];

  char* ws = (char*)d_ws;
  const size_t OFF_XAUG  = 0;          // 8192x1024 bf16 = 16777216
  const size_t OFF_XOAUG = 16777216;   // 8192x1024 bf16 = 16777216
  const size_t OFF_WQKV  = 33554432;   // 3072x1024 bf16 = 6291456
  const size_t OFF_WOEFF = 39845888;   // 1024x1024 bf16 = 2097152
  const size_t OFF_BIASC = 41943040;   // 3072 f32
  const size_t OFF_QB    = 41955328;   // 16777216
  const size_t OFF_KB    = 58732544;   // 16777216
  const size_t OFF_VT    = 75509760;   // 16777216
  const size_t OFF_CS    = 92286976;   // 131072 float2 = 1 MiB

  short* xaug  = (short*)(ws + OFF_XAUG);
  short* xoaug = (short*)(ws + OFF_XOAUG);
  short* wqkv  = (short*)(ws + OFF_WQKV);
  short* woeff = (short*)(ws + OFF_WOEFF);
  float* biasc = (float*)(ws + OFF_BIASC);
  short* qb    = (short*)(ws + OFF_QB);
  short* kb    = (short*)(ws + OFF_KB);
  short* vt    = (short*)(ws + OFF_VT);
  float* cs2   = (float*)(ws + OFF_CS);

  // 12717056 elements total = exactly 49676 blocks
  prep_k<<<49676, 256, 0, stream>>>(x, wq, wk, wv, wo, wqb,
                                    lq1, lq2, lk1, lk2, lv1, lv2, lo1, lo2,
                                    fc, fs,
                                    xaug, wqkv, woeff, biasc, cs2);
  // fused QKV projection + bias + RoPE -> qb,kb (B,H,S,HD), vt (B,H,HD,S)
  gemm_bt<2><<<dim3(24, 64), 256, 0, stream>>>(xaug, 1024, wqkv, 1024, 3072, 1024,
                                               biasc, nullptr, 0, 0, qb, kb, vt,
                                               cs2);
  // flash attention -> xoaug (plain 1024-stride)
  flash_k<<<dim3(16, 32), 256, 0, stream>>>(qb, kb, vt, xoaug);
  // final projection (wo_eff includes LoRA) -> d_out (fp32)
  gemm_bt<0><<<dim3(8, 64), 256, 0, stream>>>(xoaug, 1024, woeff, 1024, 1024, 1024,
                                              wob, d_out, 1024, 0,
                                              nullptr, nullptr, nullptr, nullptr);
}